// Round 10
// baseline (134.685 us; speedup 1.0000x reference)
//
#include <hip/hip_runtime.h>
#include <math.h>

#define NN 64      // nodes
#define NF 64      // input features (= K of main GEMM)
#define NE 128     // embed
#define NH 256     // hidden
#define NA 6       // atoms
#define NB 4096    // batch
#define NT (NB*NN) // tokens = 262144

// ---- workspace layout (float offsets) ----
#define OFF_BE2    20480u     // 64*256 fp32
#define OFF_BATTN  36864u     // 6 (pad 8)
#define OFF_S      36872u     // 64
#define OFF_WATTNF 36944u     // 2048 fl = 4096 bf16 (GEMM2 A-frag: [j>>3][a16][j&7])
#define OFF_XBF    38992u     // 131072 fl = x bf16 in B-frag order [bt][nf][kk][l][8]
#define OFF_WE2F   170064u    // 2097152 fl = We2 bf16 in A-frag order [n][w][mf][kk][l][8]
#define OFF_ARAW   2267216u   // 2097152 fl = [b][n][8]
// end 4364368 floats = 17.5 MB

typedef __attribute__((ext_vector_type(8))) short short8;
typedef __attribute__((ext_vector_type(4))) float f32x4;
typedef __attribute__((ext_vector_type(4))) unsigned short us4;

static __device__ __forceinline__ unsigned short bf16r(float f) {
    unsigned u = __float_as_uint(f);
    return (unsigned short)((u + 0x7FFFu + ((u >> 16) & 1u)) >> 16);
}
static __device__ __forceinline__ unsigned bfpack(float lo, float hi) {
    return (unsigned)bf16r(lo) | ((unsigned)bf16r(hi) << 16);
}

// ---------------------------------------------------------------- kP (fused prep):
// bx 0..255   : (n = bx>>2, jq = bx&3) We2 GEMM -> frag-order bf16 + be2 fp32
// bx 256..383 : x -> bf16 in B-frag order
// bx 384..387 : Wattn (jt = bx-384) -> frag order; 384 also battn + zero S
__global__ __launch_bounds__(256) void kP(
        const float* __restrict__ x, const float* __restrict__ Wemb,
        const float* __restrict__ bemb, const float* __restrict__ adjw,
        const float* __restrict__ W1, const float* __restrict__ b1,
        const float* __restrict__ basis, const float* __restrict__ Wq,
        const float* __restrict__ Wk, const float* __restrict__ W2,
        const float* __restrict__ b2, float* __restrict__ ws) {
    __shared__ float sh[17024];
    const int bx = blockIdx.x, t = threadIdx.x;

    if (bx < 256) {
        // ---- We2 GEMM block: n, j-quarter (64 j x 64 f, K=128) ----
        const int n = bx >> 2, jq = bx & 3;
        float* WmT = sh;              // [128 e][68]  (transposed mix, padded)
        float* W1q = sh + 8704;       // [128 e][64 j]
        float* bm  = sh + 16896;      // [128 e]
        const int r = n >> 3, c = n & 7;
        int ml[4]; int nm = 0;
        if (r > 0) ml[nm++] = n - 8;
        if (r < 7) ml[nm++] = n + 8;
        if (c > 0) ml[nm++] = n - 1;
        if (c < 7) ml[nm++] = n + 1;
        float av[4]; float asum = 0.f;
        for (int d = 0; d < nm; ++d) {
            av[d] = 1.f / (1.f + expf(-adjw[n * NN + ml[d]]));
            asum += av[d];
        }
        const float ainv = 1.f / fmaxf(asum, 1e-6f);
        for (int d = 0; d < nm; ++d) av[d] *= ainv;

        #pragma unroll 4
        for (int i = 0; i < 32; ++i) {              // WmT[e][f]
            int idx = i * 256 + t;
            int f = idx >> 7, e = idx & 127;
            float acc = 0.f;
            for (int d = 0; d < nm; ++d)
                acc = fmaf(av[d], Wemb[(size_t)f * (NN * NE) + ml[d] * NE + e], acc);
            WmT[e * 68 + f] = acc;
        }
        if (t < 128) {
            float accb = 0.f;
            for (int d = 0; d < nm; ++d)
                accb = fmaf(av[d], bemb[ml[d] * NE + t], accb);
            bm[t] = accb;
        }
        #pragma unroll 4
        for (int i = 0; i < 32; ++i) {              // W1q[e][j]
            int idx = i * 256 + t;
            int e = idx >> 6, j6 = idx & 63;
            W1q[e * 64 + j6] = W1[(size_t)e * NH + jq * 64 + j6];
        }
        __syncthreads();

        const int jg = t & 15, fg = t >> 4;         // j-quad, f-quad
        float acc[4][4];
        #pragma unroll
        for (int jj = 0; jj < 4; ++jj)
            #pragma unroll
            for (int ff = 0; ff < 4; ++ff) acc[jj][ff] = 0.f;
        float accb[4] = {0.f, 0.f, 0.f, 0.f};
        #pragma unroll 2
        for (int e = 0; e < 128; ++e) {
            float4 w1 = *(const float4*)&W1q[e * 64 + jg * 4];
            float4 wm = *(const float4*)&WmT[e * 68 + fg * 4];
            const float w1v[4] = {w1.x, w1.y, w1.z, w1.w};
            const float wmv[4] = {wm.x, wm.y, wm.z, wm.w};
            #pragma unroll
            for (int jj = 0; jj < 4; ++jj)
                #pragma unroll
                for (int ff = 0; ff < 4; ++ff)
                    acc[jj][ff] = fmaf(w1v[jj], wmv[ff], acc[jj][ff]);
            if (fg == 0) {
                float bb = bm[e];
                #pragma unroll
                for (int jj = 0; jj < 4; ++jj) accb[jj] = fmaf(bb, w1v[jj], accb[jj]);
            }
        }
        // frag-order write: chunk(j, c=f>>3) at [n][jq][mf][kk][l=(c&3)*16+(j&15)]
        unsigned short* wf = (unsigned short*)(ws + OFF_WE2F);
        const int mf = jg >> 2, kk = fg >> 3, lbase = ((fg >> 1) & 3) * 16;
        const size_t cb = ((((size_t)n * 4 + jq) * 4 + mf) * 2 + kk) * 64;
        #pragma unroll
        for (int jj = 0; jj < 4; ++jj) {
            int jl = jg * 4 + jj;
            size_t off = (cb + lbase + (jl & 15)) * 8 + (fg & 1) * 4;
            us4 pk;
            #pragma unroll
            for (int ff = 0; ff < 4; ++ff) pk[ff] = bf16r(acc[jj][ff]);
            *(us4*)(wf + off) = pk;
        }
        if (fg == 0) {
            #pragma unroll
            for (int jj = 0; jj < 4; ++jj) {
                int j = jq * 64 + jg * 4 + jj;
                ws[OFF_BE2 + n * NH + j] = accb[jj] + b1[j];
            }
        }
        return;
    }
    if (bx < 384) {
        // ---- x -> bf16 B-frag order ----
        int g = (bx - 256) * 256 + t;               // 0..32767
        int b = g >> 3, ko = g & 7;
        float4 v0 = ((const float4*)x)[b * 16 + ko * 2];
        float4 v1 = ((const float4*)x)[b * 16 + ko * 2 + 1];
        union { unsigned u[4]; short8 v; } cv;
        cv.u[0] = bfpack(v0.x, v0.y); cv.u[1] = bfpack(v0.z, v0.w);
        cv.u[2] = bfpack(v1.x, v1.y); cv.u[3] = bfpack(v1.z, v1.w);
        int bt = b >> 6, nf = (b >> 4) & 3, kk = ko >> 2, l = (ko & 3) * 16 + (b & 15);
        ((short8*)(ws + OFF_XBF))[(((size_t)bt * 4 + nf) * 2 + kk) * 64 + l] = cv.v;
        return;
    }
    // ---- Wattn blocks: jt = bx-384 handles j = jt*64..+63 ----
    const int jt = bx - 384;
    float* Ks  = sh;            // [6][128]
    float* WqK = sh + 768;      // [128][8] (pad)
    float* W2t = sh + 1792;     // [64][129]
    for (int q = t; q < NA * NE; q += 256) {
        int a = q >> 7, e2 = q & 127;
        float acc = 0.f;
        for (int e = 0; e < NE; ++e) acc = fmaf(basis[a * NE + e], Wk[e * NE + e2], acc);
        Ks[a * NE + e2] = acc;
    }
    __syncthreads();
    for (int q = t; q < NE * NA; q += 256) {
        int e = q / NA, a = q - e * NA;
        float acc = 0.f;
        for (int e2 = 0; e2 < NE; ++e2) acc = fmaf(Wq[e * NE + e2], Ks[a * NE + e2], acc);
        WqK[e * 8 + a] = acc;
    }
    __syncthreads();
    for (int i = 0; i < 32; ++i) {                  // stage W2 rows jt*64..+63
        int idx = i * 256 + t;
        int jr = idx >> 7, e = idx & 127;
        W2t[jr * 129 + e] = W2[(size_t)(jt * 64 + jr) * NE + e];
    }
    __syncthreads();
    const float scale = 1.f / (sqrtf(128.f) + 1e-8f);
    unsigned short* wf16 = (unsigned short*)(ws + OFF_WATTNF);
    const int jl = t & 63, ag = t >> 6;
    const int j = jt * 64 + jl;
    const int na = (ag < 2) ? 2 : 1;
    for (int ai = 0; ai < na; ++ai) {
        int a = ag + ai * 4;
        float acc = 0.f;
        for (int e = 0; e < NE; ++e)
            acc = fmaf(W2t[jl * 129 + e], WqK[e * 8 + a], acc);
        wf16[((j >> 3) * 16 + a) * 8 + (j & 7)] = bf16r(acc * scale);
    }
    if (ag == 3) wf16[((j >> 3) * 16 + 6) * 8 + (j & 7)] = bf16r(1.0f);  // ones col
    for (int a7 = 7 + ag; a7 < 16; a7 += 4)
        wf16[((j >> 3) * 16 + a7) * 8 + (j & 7)] = 0;
    if (jt == 0) {
        __syncthreads();
        if (t < NA) {
            float acc = 0.f;
            for (int e = 0; e < NE; ++e) acc = fmaf(b2[e], WqK[e * 8 + t], acc);
            ws[OFF_BATTN + t] = acc * scale;
        }
        if (t < 64) ws[OFF_S + t] = 0.f;
    }
}

// ---------------------------------------------------------------- A:
// per (bt,n): GEMM1 (MFMA, frag loads fully coalesced): hT = We2^T @ x^T,
// relu+bias; GEMM2 (MFMA): attnT[a][b] (ones col -> hsum). ARAW [b][n][8].
__global__ __launch_bounds__(256) void kA(float* __restrict__ ws) {
    const int bt = blockIdx.x, n = blockIdx.y;
    const int t = threadIdx.x, w = t >> 6, l = t & 63, lo = l & 15, hi = l >> 4;
    const int j0 = w * 64;
    __shared__ float be2s[256];
    __shared__ float red[4][16][64];

    be2s[t] = ws[OFF_BE2 + n * NH + t];

    const short8* Af = (const short8*)(ws + OFF_WE2F);
    const short8* Bf = (const short8*)(ws + OFF_XBF);
    short8 afr[4][2], bfr[4][2];
    #pragma unroll
    for (int mf = 0; mf < 4; ++mf)
        #pragma unroll
        for (int kk = 0; kk < 2; ++kk)
            afr[mf][kk] = Af[(((size_t)n * 4 + w) * 4 + mf) * 2 * 64 + (size_t)kk * 64 + l];
    #pragma unroll
    for (int nf = 0; nf < 4; ++nf)
        #pragma unroll
        for (int kk = 0; kk < 2; ++kk)
            bfr[nf][kk] = Bf[(((size_t)bt * 4 + nf) * 2 + kk) * 64 + l];

    f32x4 zero = {0.f, 0.f, 0.f, 0.f};
    f32x4 acc[4][4];
    #pragma unroll
    for (int mf = 0; mf < 4; ++mf)
        #pragma unroll
        for (int nf = 0; nf < 4; ++nf) acc[mf][nf] = zero;

    #pragma unroll
    for (int kk = 0; kk < 2; ++kk)
        #pragma unroll
        for (int mf = 0; mf < 4; ++mf)
            #pragma unroll
            for (int nf = 0; nf < 4; ++nf)
                acc[mf][nf] = __builtin_amdgcn_mfma_f32_16x16x32_bf16(
                    afr[mf][kk], bfr[nf][kk], acc[mf][nf], 0, 0, 0);

    __syncthreads();   // be2s ready

    // h = relu(acc + be2[j]); pack bf16. lane: row j = j0+mf*16+hi*4+i, col b = nf*16+lo
    unsigned P[4][4][2];
    #pragma unroll
    for (int mf = 0; mf < 4; ++mf) {
        const int jb = j0 + mf * 16 + hi * 4;
        #pragma unroll
        for (int nf = 0; nf < 4; ++nf) {
            float h0 = fmaxf(acc[mf][nf][0] + be2s[jb + 0], 0.f);
            float h1 = fmaxf(acc[mf][nf][1] + be2s[jb + 1], 0.f);
            float h2 = fmaxf(acc[mf][nf][2] + be2s[jb + 2], 0.f);
            float h3 = fmaxf(acc[mf][nf][3] + be2s[jb + 3], 0.f);
            P[mf][nf][0] = bfpack(h0, h1);
            P[mf][nf][1] = bfpack(h2, h3);
        }
    }

    // GEMM2: attnT[a16][b64] over this wave's 64 j's (K=64 -> 2 steps of 32)
    const short8* Wf = (const short8*)(ws + OFF_WATTNF);
    f32x4 acc2[4];
    #pragma unroll
    for (int nf = 0; nf < 4; ++nf) acc2[nf] = zero;
    #pragma unroll
    for (int kk2 = 0; kk2 < 2; ++kk2) {
        short8 a2 = Wf[(size_t)(w * 2 + kk2) * 64 + l];
        #pragma unroll
        for (int nf = 0; nf < 4; ++nf) {
            unsigned bq[4];
            #pragma unroll
            for (int q = 0; q < 4; ++q) {
                int s = ((hi & 1) * 2 + (q >> 1)) * 16 + lo;
                unsigned vA = (unsigned)__shfl((int)P[2 * kk2 + 0][nf][q & 1], s, 64);
                unsigned vB = (unsigned)__shfl((int)P[2 * kk2 + 1][nf][q & 1], s, 64);
                bq[q] = (hi >= 2) ? vB : vA;
            }
            union { unsigned u[4]; short8 v; } cv;
            cv.u[0] = bq[0]; cv.u[1] = bq[1]; cv.u[2] = bq[2]; cv.u[3] = bq[3];
            acc2[nf] = __builtin_amdgcn_mfma_f32_16x16x32_bf16(a2, cv.v, acc2[nf], 0, 0, 0);
        }
    }

    // cross-wave reduce
    #pragma unroll
    for (int nf = 0; nf < 4; ++nf)
        #pragma unroll
        for (int i = 0; i < 4; ++i)
            red[w][hi * 4 + i][nf * 16 + lo] = acc2[nf][i];
    __syncthreads();

    const int rb = t & 63, a0 = t >> 6, a1 = a0 + 4;
    float v0 = red[0][a0][rb] + red[1][a0][rb] + red[2][a0][rb] + red[3][a0][rb];
    float v1 = red[0][a1][rb] + red[1][a1][rb] + red[2][a1][rb] + red[3][a1][rb];
    if (a1 == 6) {   // wave 2: ones-column = h row-sums -> global S[n]
        float hs = v1;
        #pragma unroll
        for (int m = 1; m < 64; m <<= 1) hs += __shfl_xor(hs, m, 64);
        if (l == 0) atomicAdd(ws + OFF_S + n, hs);
    }
    __syncthreads();                       // done reading red
    float* red2 = &red[0][0][0];           // [64 b][8 a]
    red2[rb * 8 + a0] = v0;
    red2[rb * 8 + a1] = v1;
    __syncthreads();
    if (t < 128) {                         // ARAW[b][n][8]
        int i = t >> 1, half = t & 1;
        float4 v = *(const float4*)&red2[i * 8 + half * 4];
        *(float4*)(ws + OFF_ARAW + ((size_t)(bt * 64 + i) * 64 + n) * 8 + half * 4) = v;
    }
}

// ---------------------------------------------------------------- C:
// block = one batch row b: thread0 scalar gate chain (c), contiguous 2 KB
// ARAW read via LDS, softmax(6) per token, 32 KB contiguous output write.
__global__ __launch_bounds__(256) void kC(const float* __restrict__ ws,
                                          const float* __restrict__ basis,
                                          const float* __restrict__ mW1, const float* __restrict__ mb1,
                                          const float* __restrict__ mW2, const float* __restrict__ mb2,
                                          const float* __restrict__ gW1, const float* __restrict__ gb1,
                                          const float* __restrict__ gW2, const float* __restrict__ gb2,
                                          float* __restrict__ out) {
    const int b = blockIdx.x;
    const int t = threadIdx.x;
    __shared__ float ars[512];
    __shared__ float sw[64][8];
    __shared__ float bs[6][128];
    __shared__ float csh;
    if (t < 128)
        ((float4*)ars)[t] = ((const float4*)(ws + OFF_ARAW + (size_t)b * 512))[t];
    for (int q = t; q < NA * NE; q += 256) bs[q >> 7][q & 127] = basis[q];
    if (t == 0) {   // scalar gate chain
        float S = 0.f;
        for (int i = 0; i < 64; ++i) S += ws[OFF_S + i];
        float s = S / ((float)NB * NN * NH);
        float accm = mb2[0];
        for (int i = 0; i < 8; ++i) accm += fmaxf(s * mW1[i] + mb1[i], 0.f) * mW2[i];
        float m = 1.f / (1.f + expf(-accm));
        float state = 0.9f * 0.5f + 0.1f * m;
        float c1 = 1.f + 0.1f * (state - 0.5f);
        float sg = c1 * s;
        float accg = gb2[0];
        for (int i = 0; i < 16; ++i) accg += fmaxf(sg * gW1[i] + gb1[i], 0.f) * gW2[i];
        float g = 1.f / (1.f + expf(-accg));
        csh = c1 * g;
    }
    __syncthreads();
    if (t < 64) {
        const float c = csh;
        float at[6], mx = -1e30f;
        #pragma unroll
        for (int a = 0; a < 6; ++a) {
            at[a] = fmaf(c, ars[t * 8 + a], ws[OFF_BATTN + a]);
            mx = fmaxf(mx, at[a]);
        }
        float ex[6], ssum = 0.f;
        #pragma unroll
        for (int a = 0; a < 6; ++a) { ex[a] = expf(at[a] - mx); ssum += ex[a]; }
        float inv = 1.f / ssum;
        #pragma unroll
        for (int a = 0; a < 6; ++a) sw[t][a] = ex[a] * inv;
    }
    __syncthreads();
    float* op = out + (size_t)b * (NN * NE);
    #pragma unroll
    for (int i = 0; i < 8; ++i) {
        int idx = i * 1024 + t * 4;          // 0..8191
        int n = idx >> 7, e = idx & 127;
        float wv[6];
        #pragma unroll
        for (int a = 0; a < 6; ++a) wv[a] = sw[n][a];
        float4 r;
        #pragma unroll
        for (int cc = 0; cc < 4; ++cc) {
            float o = 0.f;
            #pragma unroll
            for (int a = 0; a < 6; ++a) o = fmaf(wv[a], bs[a][e + cc], o);
            ((float*)&r)[cc] = fminf(fmaxf(o, -3.f), 3.f);
        }
        *(float4*)(op + idx) = r;
    }
}

extern "C" void kernel_launch(void* const* d_in, const int* in_sizes, int n_in,
                              void* d_out, int out_size, void* d_ws, size_t ws_size,
                              hipStream_t stream) {
    const float* x     = (const float*)d_in[0];
    const float* Wemb  = (const float*)d_in[1];
    const float* bemb  = (const float*)d_in[2];
    const float* adjw  = (const float*)d_in[3];
    const float* W1    = (const float*)d_in[4];
    const float* b1    = (const float*)d_in[5];
    const float* W2    = (const float*)d_in[6];
    const float* b2    = (const float*)d_in[7];
    const float* basis = (const float*)d_in[8];
    const float* Wq    = (const float*)d_in[9];
    const float* Wk    = (const float*)d_in[10];
    const float* mW1   = (const float*)d_in[11];
    const float* mb1   = (const float*)d_in[12];
    const float* mW2   = (const float*)d_in[13];
    const float* mb2   = (const float*)d_in[14];
    const float* gW1   = (const float*)d_in[15];
    const float* gb1   = (const float*)d_in[16];
    const float* gW2   = (const float*)d_in[17];
    const float* gb2   = (const float*)d_in[18];
    float* ws  = (float*)d_ws;
    float* out = (float*)d_out;

    kP<<<388, 256, 0, stream>>>(x, Wemb, bemb, adjw, W1, b1, basis, Wq, Wk, W2, b2, ws);
    kA<<<dim3(64, 64), 256, 0, stream>>>(ws);
    kC<<<NB, 256, 0, stream>>>(ws, basis, mW1, mb1, mW2, mb2, gW1, gb1, gW2, gb2, out);
}

// Round 11
// 120.291 us; speedup vs baseline: 1.1197x; 1.1197x over previous
//
#include <hip/hip_runtime.h>
#include <math.h>

#define NN 64      // nodes
#define NF 64      // input features (= K of main GEMM)
#define NE 128     // embed
#define NH 256     // hidden
#define NA 6       // atoms
#define NB 4096    // batch
#define NT (NB*NN) // tokens = 262144

// ---- workspace layout (float offsets) ----
#define OFF_WATTN16 8192u     // 2048 fl (written by kP, unused by this kA - reserved)
#define OFF_BE2    20480u     // 64*256 fp32
#define OFF_BATTN  36864u     // 6 (pad 8)
#define OFF_S      36872u     // 64
#define OFF_WATTNF 36944u     // 2048 fl = 4096 bf16 (GEMM2 A-frag: [j>>3][a16][j&7])
#define OFF_XBF    38992u     // 131072 fl = x bf16 in B-frag order [bt][nf][kk][l][8]
#define OFF_WE2F   170064u    // 2097152 fl = We2 bf16 in A-frag order [n][w][mf][kk][l][8]
#define OFF_ARAW   2267216u   // 2097152 fl = [b][n][8]
// end 4364368 floats = 17.5 MB

typedef __attribute__((ext_vector_type(8))) short short8;
typedef __attribute__((ext_vector_type(4))) float f32x4;
typedef __attribute__((ext_vector_type(4))) unsigned short us4;

static __device__ __forceinline__ unsigned short bf16r(float f) {
    unsigned u = __float_as_uint(f);
    return (unsigned short)((u + 0x7FFFu + ((u >> 16) & 1u)) >> 16);
}
static __device__ __forceinline__ unsigned bfpack(float lo, float hi) {
    return (unsigned)bf16r(lo) | ((unsigned)bf16r(hi) << 16);
}

// ---------------------------------------------------------------- kP (fused prep, 512 thr):
// bx 0..255   : (n = bx>>2, jq = bx&3) We2 GEMM -> frag-order bf16 + be2 fp32
// bx 256..319 : x -> bf16 in B-frag order
// bx 320..323 : Wattn (jt) -> frag layouts; jt==0 also battn + zero S
__global__ __launch_bounds__(512) void kP(
        const float* __restrict__ x, const float* __restrict__ Wemb,
        const float* __restrict__ bemb, const float* __restrict__ adjw,
        const float* __restrict__ W1, const float* __restrict__ b1,
        const float* __restrict__ basis, const float* __restrict__ Wq,
        const float* __restrict__ Wk, const float* __restrict__ W2,
        const float* __restrict__ b2, float* __restrict__ ws) {
    __shared__ float sh[17024];
    const int bx = blockIdx.x, t = threadIdx.x;

    if (bx < 256) {
        // ---- We2 GEMM block: n, j-quarter (64 j x 64 f, K=128) ----
        const int n = bx >> 2, jq = bx & 3;
        float* WmT = sh;              // [128 e][68]  (transposed mix, padded)
        float* W1q = sh + 8704;       // [128 e][64 j]
        float* bm  = sh + 16896;      // [128 e]
        const int r = n >> 3, c = n & 7;
        int ml[4]; int nm = 0;
        if (r > 0) ml[nm++] = n - 8;
        if (r < 7) ml[nm++] = n + 8;
        if (c > 0) ml[nm++] = n - 1;
        if (c < 7) ml[nm++] = n + 1;
        float av[4]; float asum = 0.f;
        for (int d = 0; d < nm; ++d) {
            av[d] = 1.f / (1.f + expf(-adjw[n * NN + ml[d]]));
            asum += av[d];
        }
        const float ainv = 1.f / fmaxf(asum, 1e-6f);
        for (int d = 0; d < nm; ++d) av[d] *= ainv;

        #pragma unroll 4
        for (int i = 0; i < 16; ++i) {              // WmT[e][f]
            int idx = i * 512 + t;
            int f = idx >> 7, e = idx & 127;
            float acc = 0.f;
            for (int d = 0; d < nm; ++d)
                acc = fmaf(av[d], Wemb[(size_t)f * (NN * NE) + ml[d] * NE + e], acc);
            WmT[e * 68 + f] = acc;
        }
        if (t < 128) {
            float accb = 0.f;
            for (int d = 0; d < nm; ++d)
                accb = fmaf(av[d], bemb[ml[d] * NE + t], accb);
            bm[t] = accb;
        }
        #pragma unroll 4
        for (int i = 0; i < 16; ++i) {              // W1q[e][j]
            int idx = i * 512 + t;
            int e = idx >> 6, j6 = idx & 63;
            W1q[e * 64 + j6] = W1[(size_t)e * NH + jq * 64 + j6];
        }
        __syncthreads();

        const int jg = t & 15, fg = t >> 4;         // j-quad, f-pair
        float acc[4][2];
        #pragma unroll
        for (int jj = 0; jj < 4; ++jj) { acc[jj][0] = 0.f; acc[jj][1] = 0.f; }
        float accb[4] = {0.f, 0.f, 0.f, 0.f};
        #pragma unroll 4
        for (int e = 0; e < 128; ++e) {
            float4 w1 = *(const float4*)&W1q[e * 64 + jg * 4];
            float2 wm = *(const float2*)&WmT[e * 68 + fg * 2];
            const float w1v[4] = {w1.x, w1.y, w1.z, w1.w};
            #pragma unroll
            for (int jj = 0; jj < 4; ++jj) {
                acc[jj][0] = fmaf(w1v[jj], wm.x, acc[jj][0]);
                acc[jj][1] = fmaf(w1v[jj], wm.y, acc[jj][1]);
            }
            if (fg == 0) {
                float bb = bm[e];
                #pragma unroll
                for (int jj = 0; jj < 4; ++jj) accb[jj] = fmaf(bb, w1v[jj], accb[jj]);
            }
        }
        // frag-order write: f-pair (e0, e0+1) of chunk (n, jq, mf, kk) lane (hi,lo)
        unsigned short* wf = (unsigned short*)(ws + OFF_WE2F);
        const int mfj = jg >> 2, kk = fg >> 4;
        const int lbase = ((fg >> 2) & 3) * 16, e0 = (fg & 3) * 2;
        const size_t cb = ((((size_t)n * 4 + jq) * 4 + mfj) * 2 + kk) * 64;
        #pragma unroll
        for (int jj = 0; jj < 4; ++jj) {
            int l16 = (jg * 4 + jj) & 15;
            *(unsigned*)(wf + (cb + lbase + l16) * 8 + e0) = bfpack(acc[jj][0], acc[jj][1]);
        }
        if (fg == 0) {
            #pragma unroll
            for (int jj = 0; jj < 4; ++jj) {
                int j = jq * 64 + jg * 4 + jj;
                ws[OFF_BE2 + n * NH + j] = accb[jj] + b1[j];
            }
        }
        return;
    }
    if (bx < 320) {
        // ---- x -> bf16 B-frag order ----
        int g = (bx - 256) * 512 + t;               // 0..32767
        int b = g >> 3, ko = g & 7;
        float4 v0 = ((const float4*)x)[b * 16 + ko * 2];
        float4 v1 = ((const float4*)x)[b * 16 + ko * 2 + 1];
        union { unsigned u[4]; short8 v; } cv;
        cv.u[0] = bfpack(v0.x, v0.y); cv.u[1] = bfpack(v0.z, v0.w);
        cv.u[2] = bfpack(v1.x, v1.y); cv.u[3] = bfpack(v1.z, v1.w);
        int bt = b >> 6, nf = (b >> 4) & 3, kk = ko >> 2, l = (ko & 3) * 16 + (b & 15);
        ((short8*)(ws + OFF_XBF))[(((size_t)bt * 4 + nf) * 2 + kk) * 64 + l] = cv.v;
        return;
    }
    // ---- Wattn blocks: jt = bx-320 handles j = jt*64..+63 ----
    const int jt = bx - 320;
    float* Ks  = sh;            // [6][128]
    float* WqK = sh + 768;      // [128][8] (pad)
    float* W2t = sh + 1792;     // [64][129]
    for (int q = t; q < NA * NE; q += 512) {
        int a = q >> 7, e2 = q & 127;
        float acc = 0.f;
        for (int e = 0; e < NE; ++e) acc = fmaf(basis[a * NE + e], Wk[e * NE + e2], acc);
        Ks[a * NE + e2] = acc;
    }
    __syncthreads();
    for (int q = t; q < NE * NA; q += 512) {
        int e = q / NA, a = q - e * NA;
        float acc = 0.f;
        for (int e2 = 0; e2 < NE; ++e2) acc = fmaf(Wq[e * NE + e2], Ks[a * NE + e2], acc);
        WqK[e * 8 + a] = acc;
    }
    __syncthreads();
    for (int i = 0; i < 16; ++i) {                  // stage W2 rows jt*64..+63
        int idx = i * 512 + t;
        int jr = idx >> 7, e = idx & 127;
        W2t[jr * 129 + e] = W2[(size_t)(jt * 64 + jr) * NE + e];
    }
    __syncthreads();
    const float scale = 1.f / (sqrtf(128.f) + 1e-8f);
    unsigned short* wf16 = (unsigned short*)(ws + OFF_WATTNF);
    if (t < 256) {
        const int jl = t & 63, ag = t >> 6;
        const int j = jt * 64 + jl;
        const int na = (ag < 2) ? 2 : 1;
        for (int ai = 0; ai < na; ++ai) {
            int a = ag + ai * 4;
            float acc = 0.f;
            for (int e = 0; e < NE; ++e)
                acc = fmaf(W2t[jl * 129 + e], WqK[e * 8 + a], acc);
            wf16[((j >> 3) * 16 + a) * 8 + (j & 7)] = bf16r(acc * scale);
        }
        if (ag == 3) wf16[((j >> 3) * 16 + 6) * 8 + (j & 7)] = bf16r(1.0f);  // ones col
        for (int a7 = 7 + ag; a7 < 16; a7 += 4)
            wf16[((j >> 3) * 16 + a7) * 8 + (j & 7)] = 0;
    }
    if (jt == 0) {
        __syncthreads();
        if (t < NA) {
            float acc = 0.f;
            for (int e = 0; e < NE; ++e) acc = fmaf(b2[e], WqK[e * 8 + t], acc);
            ws[OFF_BATTN + t] = acc * scale;
        }
        if (t < 64) ws[OFF_S + t] = 0.f;
    }
}

// ---------------------------------------------------------------- A:
// per (bt,n): GEMM1 (MFMA, frag loads fully coalesced): hT = We2^T @ x^T,
// relu+bias; GEMM2 (MFMA): attnT[a][b] (ones col -> hsum). ARAW [b][n][8].
__global__ __launch_bounds__(256) void kA(float* __restrict__ ws) {
    const int bt = blockIdx.x, n = blockIdx.y;
    const int t = threadIdx.x, w = t >> 6, l = t & 63, lo = l & 15, hi = l >> 4;
    const int j0 = w * 64;
    __shared__ float be2s[256];
    __shared__ float red[4][16][64];

    be2s[t] = ws[OFF_BE2 + n * NH + t];

    const short8* Af = (const short8*)(ws + OFF_WE2F);
    const short8* Bf = (const short8*)(ws + OFF_XBF);
    short8 afr[4][2], bfr[4][2];
    #pragma unroll
    for (int mf = 0; mf < 4; ++mf)
        #pragma unroll
        for (int kk = 0; kk < 2; ++kk)
            afr[mf][kk] = Af[(((size_t)n * 4 + w) * 4 + mf) * 2 * 64 + (size_t)kk * 64 + l];
    #pragma unroll
    for (int nf = 0; nf < 4; ++nf)
        #pragma unroll
        for (int kk = 0; kk < 2; ++kk)
            bfr[nf][kk] = Bf[(((size_t)bt * 4 + nf) * 2 + kk) * 64 + l];

    f32x4 zero = {0.f, 0.f, 0.f, 0.f};
    f32x4 acc[4][4];
    #pragma unroll
    for (int mf = 0; mf < 4; ++mf)
        #pragma unroll
        for (int nf = 0; nf < 4; ++nf) acc[mf][nf] = zero;

    #pragma unroll
    for (int kk = 0; kk < 2; ++kk)
        #pragma unroll
        for (int mf = 0; mf < 4; ++mf)
            #pragma unroll
            for (int nf = 0; nf < 4; ++nf)
                acc[mf][nf] = __builtin_amdgcn_mfma_f32_16x16x32_bf16(
                    afr[mf][kk], bfr[nf][kk], acc[mf][nf], 0, 0, 0);

    __syncthreads();   // be2s ready

    // h = relu(acc + be2[j]); pack bf16. lane: row j = j0+mf*16+hi*4+i, col b = nf*16+lo
    unsigned P[4][4][2];
    #pragma unroll
    for (int mf = 0; mf < 4; ++mf) {
        const int jb = j0 + mf * 16 + hi * 4;
        #pragma unroll
        for (int nf = 0; nf < 4; ++nf) {
            float h0 = fmaxf(acc[mf][nf][0] + be2s[jb + 0], 0.f);
            float h1 = fmaxf(acc[mf][nf][1] + be2s[jb + 1], 0.f);
            float h2 = fmaxf(acc[mf][nf][2] + be2s[jb + 2], 0.f);
            float h3 = fmaxf(acc[mf][nf][3] + be2s[jb + 3], 0.f);
            P[mf][nf][0] = bfpack(h0, h1);
            P[mf][nf][1] = bfpack(h2, h3);
        }
    }

    // GEMM2: attnT[a16][b64] over this wave's 64 j's (K=64 -> 2 steps of 32)
    const short8* Wf = (const short8*)(ws + OFF_WATTNF);
    f32x4 acc2[4];
    #pragma unroll
    for (int nf = 0; nf < 4; ++nf) acc2[nf] = zero;
    #pragma unroll
    for (int kk2 = 0; kk2 < 2; ++kk2) {
        short8 a2 = Wf[(size_t)(w * 2 + kk2) * 64 + l];
        #pragma unroll
        for (int nf = 0; nf < 4; ++nf) {
            unsigned bq[4];
            #pragma unroll
            for (int q = 0; q < 4; ++q) {
                int s = ((hi & 1) * 2 + (q >> 1)) * 16 + lo;
                unsigned vA = (unsigned)__shfl((int)P[2 * kk2 + 0][nf][q & 1], s, 64);
                unsigned vB = (unsigned)__shfl((int)P[2 * kk2 + 1][nf][q & 1], s, 64);
                bq[q] = (hi >= 2) ? vB : vA;
            }
            union { unsigned u[4]; short8 v; } cv;
            cv.u[0] = bq[0]; cv.u[1] = bq[1]; cv.u[2] = bq[2]; cv.u[3] = bq[3];
            acc2[nf] = __builtin_amdgcn_mfma_f32_16x16x32_bf16(a2, cv.v, acc2[nf], 0, 0, 0);
        }
    }

    // cross-wave reduce
    #pragma unroll
    for (int nf = 0; nf < 4; ++nf)
        #pragma unroll
        for (int i = 0; i < 4; ++i)
            red[w][hi * 4 + i][nf * 16 + lo] = acc2[nf][i];
    __syncthreads();

    const int rb = t & 63, a0 = t >> 6, a1 = a0 + 4;
    float v0 = red[0][a0][rb] + red[1][a0][rb] + red[2][a0][rb] + red[3][a0][rb];
    float v1 = red[0][a1][rb] + red[1][a1][rb] + red[2][a1][rb] + red[3][a1][rb];
    if (a1 == 6) {   // wave 2: ones-column = h row-sums -> global S[n]
        float hs = v1;
        #pragma unroll
        for (int m = 1; m < 64; m <<= 1) hs += __shfl_xor(hs, m, 64);
        if (l == 0) atomicAdd(ws + OFF_S + n, hs);
    }
    __syncthreads();                       // done reading red
    float* red2 = &red[0][0][0];           // [64 b][8 a]
    red2[rb * 8 + a0] = v0;
    red2[rb * 8 + a1] = v1;
    __syncthreads();
    if (t < 128) {                         // ARAW[b][n][8]
        int i = t >> 1, half = t & 1;
        float4 v = *(const float4*)&red2[i * 8 + half * 4];
        *(float4*)(ws + OFF_ARAW + ((size_t)(bt * 64 + i) * 64 + n) * 8 + half * 4) = v;
    }
}

// ---------------------------------------------------------------- C:
// block = one batch row b: thread0 scalar gate chain (c), contiguous 2 KB
// ARAW read via LDS, softmax(6) per token, 32 KB contiguous output write.
__global__ __launch_bounds__(256) void kC(const float* __restrict__ ws,
                                          const float* __restrict__ basis,
                                          const float* __restrict__ mW1, const float* __restrict__ mb1,
                                          const float* __restrict__ mW2, const float* __restrict__ mb2,
                                          const float* __restrict__ gW1, const float* __restrict__ gb1,
                                          const float* __restrict__ gW2, const float* __restrict__ gb2,
                                          float* __restrict__ out) {
    const int b = blockIdx.x;
    const int t = threadIdx.x;
    __shared__ float ars[512];
    __shared__ float sw[64][8];
    __shared__ float bs[6][128];
    __shared__ float csh;
    if (t < 128)
        ((float4*)ars)[t] = ((const float4*)(ws + OFF_ARAW + (size_t)b * 512))[t];
    for (int q = t; q < NA * NE; q += 256) bs[q >> 7][q & 127] = basis[q];
    if (t == 0) {   // scalar gate chain
        float S = 0.f;
        for (int i = 0; i < 64; ++i) S += ws[OFF_S + i];
        float s = S / ((float)NB * NN * NH);
        float accm = mb2[0];
        for (int i = 0; i < 8; ++i) accm += fmaxf(s * mW1[i] + mb1[i], 0.f) * mW2[i];
        float m = 1.f / (1.f + expf(-accm));
        float state = 0.9f * 0.5f + 0.1f * m;
        float c1 = 1.f + 0.1f * (state - 0.5f);
        float sg = c1 * s;
        float accg = gb2[0];
        for (int i = 0; i < 16; ++i) accg += fmaxf(sg * gW1[i] + gb1[i], 0.f) * gW2[i];
        float g = 1.f / (1.f + expf(-accg));
        csh = c1 * g;
    }
    __syncthreads();
    if (t < 64) {
        const float c = csh;
        float at[6], mx = -1e30f;
        #pragma unroll
        for (int a = 0; a < 6; ++a) {
            at[a] = fmaf(c, ars[t * 8 + a], ws[OFF_BATTN + a]);
            mx = fmaxf(mx, at[a]);
        }
        float ex[6], ssum = 0.f;
        #pragma unroll
        for (int a = 0; a < 6; ++a) { ex[a] = expf(at[a] - mx); ssum += ex[a]; }
        float inv = 1.f / ssum;
        #pragma unroll
        for (int a = 0; a < 6; ++a) sw[t][a] = ex[a] * inv;
    }
    __syncthreads();
    float* op = out + (size_t)b * (NN * NE);
    #pragma unroll
    for (int i = 0; i < 8; ++i) {
        int idx = i * 1024 + t * 4;          // 0..8191
        int n = idx >> 7, e = idx & 127;
        float wv[6];
        #pragma unroll
        for (int a = 0; a < 6; ++a) wv[a] = sw[n][a];
        float4 r;
        #pragma unroll
        for (int cc = 0; cc < 4; ++cc) {
            float o = 0.f;
            #pragma unroll
            for (int a = 0; a < 6; ++a) o = fmaf(wv[a], bs[a][e + cc], o);
            ((float*)&r)[cc] = fminf(fmaxf(o, -3.f), 3.f);
        }
        *(float4*)(op + idx) = r;
    }
}

extern "C" void kernel_launch(void* const* d_in, const int* in_sizes, int n_in,
                              void* d_out, int out_size, void* d_ws, size_t ws_size,
                              hipStream_t stream) {
    const float* x     = (const float*)d_in[0];
    const float* Wemb  = (const float*)d_in[1];
    const float* bemb  = (const float*)d_in[2];
    const float* adjw  = (const float*)d_in[3];
    const float* W1    = (const float*)d_in[4];
    const float* b1    = (const float*)d_in[5];
    const float* W2    = (const float*)d_in[6];
    const float* b2    = (const float*)d_in[7];
    const float* basis = (const float*)d_in[8];
    const float* Wq    = (const float*)d_in[9];
    const float* Wk    = (const float*)d_in[10];
    const float* mW1   = (const float*)d_in[11];
    const float* mb1   = (const float*)d_in[12];
    const float* mW2   = (const float*)d_in[13];
    const float* mb2   = (const float*)d_in[14];
    const float* gW1   = (const float*)d_in[15];
    const float* gb1   = (const float*)d_in[16];
    const float* gW2   = (const float*)d_in[17];
    const float* gb2   = (const float*)d_in[18];
    float* ws  = (float*)d_ws;
    float* out = (float*)d_out;

    kP<<<324, 512, 0, stream>>>(x, Wemb, bemb, adjw, W1, b1, basis, Wq, Wk, W2, b2, ws);
    kA<<<dim3(64, 64), 256, 0, stream>>>(ws);
    kC<<<NB, 256, 0, stream>>>(ws, basis, mW1, mb1, mW2, mb2, gW1, gb1, gW2, gb2, out);
}

// Round 13
// 119.420 us; speedup vs baseline: 1.1278x; 1.0073x over previous
//
#include <hip/hip_runtime.h>
#include <math.h>

#define NN 64      // nodes
#define NF 64      // input features (= K of main GEMM)
#define NE 128     // embed
#define NH 256     // hidden
#define NA 6       // atoms
#define NB 4096    // batch
#define NT (NB*NN) // tokens = 262144

// ---- workspace layout (float offsets) ----
#define OFF_WATTN16 8192u     // 2048 fl (reserved, unused by this kA)
#define OFF_BE2    20480u     // 64*256 fp32
#define OFF_BATTN  36864u     // 6 (pad 8)
#define OFF_S      36872u     // 64
#define OFF_WATTNF 36944u     // 2048 fl = 4096 bf16 (GEMM2 A-frag: [j>>3][a16][j&7])
#define OFF_XBF    38992u     // 131072 fl = x bf16 in B-frag order [bt][nf][kk][l][8]
#define OFF_WE2F   170064u    // 2097152 fl = We2 bf16 in A-frag order [n][w][mf][kk][l][8]
#define OFF_ARAW   2267216u   // 2097152 fl = [b][n][8]
// end 4364368 floats = 17.5 MB

typedef __attribute__((ext_vector_type(8))) short short8;
typedef __attribute__((ext_vector_type(4))) float f32x4;
typedef __attribute__((ext_vector_type(4))) unsigned short us4;

static __device__ __forceinline__ unsigned short bf16r(float f) {
    unsigned u = __float_as_uint(f);
    return (unsigned short)((u + 0x7FFFu + ((u >> 16) & 1u)) >> 16);
}
static __device__ __forceinline__ unsigned bfpack(float lo, float hi) {
    return (unsigned)bf16r(lo) | ((unsigned)bf16r(hi) << 16);
}

// ---------------------------------------------------------------- kP (fused prep, 512 thr):
// bx 0..255   : (n = bx>>2, jq = bx&3) We2 GEMM -> frag-order bf16 + be2 fp32
// bx 256..319 : x -> bf16 in B-frag order
// bx 320..323 : Wattn (jt) -> frag layouts; jt==0 also battn + zero S
__global__ __launch_bounds__(512) void kP(
        const float* __restrict__ x, const float* __restrict__ Wemb,
        const float* __restrict__ bemb, const float* __restrict__ adjw,
        const float* __restrict__ W1, const float* __restrict__ b1,
        const float* __restrict__ basis, const float* __restrict__ Wq,
        const float* __restrict__ Wk, const float* __restrict__ W2,
        const float* __restrict__ b2, float* __restrict__ ws) {
    __shared__ float sh[17024];
    const int bx = blockIdx.x, t = threadIdx.x;

    if (bx < 256) {
        // ---- We2 GEMM block: n, j-quarter (64 j x 64 f, K=128) ----
        const int n = bx >> 2, jq = bx & 3;
        float* WmT = sh;              // [128 e][68]  (transposed mix, padded)
        float* W1q = sh + 8704;       // [128 e][64 j]
        float* bm  = sh + 16896;      // [128 e]
        const int r = n >> 3, c = n & 7;
        int ml[4]; int nm = 0;
        if (r > 0) ml[nm++] = n - 8;
        if (r < 7) ml[nm++] = n + 8;
        if (c > 0) ml[nm++] = n - 1;
        if (c < 7) ml[nm++] = n + 1;
        float av[4]; float asum = 0.f;
        for (int d = 0; d < nm; ++d) {
            av[d] = 1.f / (1.f + expf(-adjw[n * NN + ml[d]]));
            asum += av[d];
        }
        const float ainv = 1.f / fmaxf(asum, 1e-6f);
        for (int d = 0; d < nm; ++d) av[d] *= ainv;

        #pragma unroll 4
        for (int i = 0; i < 16; ++i) {              // WmT[e][f]
            int idx = i * 512 + t;
            int f = idx >> 7, e = idx & 127;
            float acc = 0.f;
            for (int d = 0; d < nm; ++d)
                acc = fmaf(av[d], Wemb[(size_t)f * (NN * NE) + ml[d] * NE + e], acc);
            WmT[e * 68 + f] = acc;
        }
        if (t < 128) {
            float accb = 0.f;
            for (int d = 0; d < nm; ++d)
                accb = fmaf(av[d], bemb[ml[d] * NE + t], accb);
            bm[t] = accb;
        }
        #pragma unroll 4
        for (int i = 0; i < 16; ++i) {              // W1q[e][j]
            int idx = i * 512 + t;
            int e = idx >> 6, j6 = idx & 63;
            W1q[e * 64 + j6] = W1[(size_t)e * NH + jq * 64 + j6];
        }
        __syncthreads();

        const int jg = t & 15, fg = t >> 4;         // j-quad, f-pair
        float acc[4][2];
        #pragma unroll
        for (int jj = 0; jj < 4; ++jj) { acc[jj][0] = 0.f; acc[jj][1] = 0.f; }
        float accb[4] = {0.f, 0.f, 0.f, 0.f};
        #pragma unroll 4
        for (int e = 0; e < 128; ++e) {
            float4 w1 = *(const float4*)&W1q[e * 64 + jg * 4];
            float2 wm = *(const float2*)&WmT[e * 68 + fg * 2];
            const float w1v[4] = {w1.x, w1.y, w1.z, w1.w};
            #pragma unroll
            for (int jj = 0; jj < 4; ++jj) {
                acc[jj][0] = fmaf(w1v[jj], wm.x, acc[jj][0]);
                acc[jj][1] = fmaf(w1v[jj], wm.y, acc[jj][1]);
            }
            if (fg == 0) {
                float bb = bm[e];
                #pragma unroll
                for (int jj = 0; jj < 4; ++jj) accb[jj] = fmaf(bb, w1v[jj], accb[jj]);
            }
        }
        // frag-order write: f-pair (e0, e0+1) of chunk (n, jq, mf, kk) lane (hi,lo)
        unsigned short* wf = (unsigned short*)(ws + OFF_WE2F);
        const int mfj = jg >> 2, kk = fg >> 4;
        const int lbase = ((fg >> 2) & 3) * 16, e0 = (fg & 3) * 2;
        const size_t cb = ((((size_t)n * 4 + jq) * 4 + mfj) * 2 + kk) * 64;
        #pragma unroll
        for (int jj = 0; jj < 4; ++jj) {
            int l16 = (jg * 4 + jj) & 15;
            *(unsigned*)(wf + (cb + lbase + l16) * 8 + e0) = bfpack(acc[jj][0], acc[jj][1]);
        }
        if (fg == 0) {
            #pragma unroll
            for (int jj = 0; jj < 4; ++jj) {
                int j = jq * 64 + jg * 4 + jj;
                ws[OFF_BE2 + n * NH + j] = accb[jj] + b1[j];
            }
        }
        return;
    }
    if (bx < 320) {
        // ---- x -> bf16 B-frag order ----
        int g = (bx - 256) * 512 + t;               // 0..32767
        int b = g >> 3, ko = g & 7;
        float4 v0 = ((const float4*)x)[b * 16 + ko * 2];
        float4 v1 = ((const float4*)x)[b * 16 + ko * 2 + 1];
        union { unsigned u[4]; short8 v; } cv;
        cv.u[0] = bfpack(v0.x, v0.y); cv.u[1] = bfpack(v0.z, v0.w);
        cv.u[2] = bfpack(v1.x, v1.y); cv.u[3] = bfpack(v1.z, v1.w);
        int bt = b >> 6, nf = (b >> 4) & 3, kk = ko >> 2, l = (ko & 3) * 16 + (b & 15);
        ((short8*)(ws + OFF_XBF))[(((size_t)bt * 4 + nf) * 2 + kk) * 64 + l] = cv.v;
        return;
    }
    // ---- Wattn blocks: jt = bx-320 handles j = jt*64..+63 ----
    const int jt = bx - 320;
    float* Ks  = sh;            // [6][128]
    float* WqK = sh + 768;      // [128][8] (pad)
    float* W2t = sh + 1792;     // [64][129]
    for (int q = t; q < NA * NE; q += 512) {
        int a = q >> 7, e2 = q & 127;
        float acc = 0.f;
        for (int e = 0; e < NE; ++e) acc = fmaf(basis[a * NE + e], Wk[e * NE + e2], acc);
        Ks[a * NE + e2] = acc;
    }
    __syncthreads();
    for (int q = t; q < NE * NA; q += 512) {
        int e = q / NA, a = q - e * NA;
        float acc = 0.f;
        for (int e2 = 0; e2 < NE; ++e2) acc = fmaf(Wq[e * NE + e2], Ks[a * NE + e2], acc);
        WqK[e * 8 + a] = acc;
    }
    __syncthreads();
    for (int i = 0; i < 16; ++i) {                  // stage W2 rows jt*64..+63
        int idx = i * 512 + t;
        int jr = idx >> 7, e = idx & 127;
        W2t[jr * 129 + e] = W2[(size_t)(jt * 64 + jr) * NE + e];
    }
    __syncthreads();
    const float scale = 1.f / (sqrtf(128.f) + 1e-8f);
    unsigned short* wf16 = (unsigned short*)(ws + OFF_WATTNF);
    if (t < 256) {
        const int jl = t & 63, ag = t >> 6;
        const int j = jt * 64 + jl;
        const int na = (ag < 2) ? 2 : 1;
        for (int ai = 0; ai < na; ++ai) {
            int a = ag + ai * 4;
            float acc = 0.f;
            for (int e = 0; e < NE; ++e)
                acc = fmaf(W2t[jl * 129 + e], WqK[e * 8 + a], acc);
            wf16[((j >> 3) * 16 + a) * 8 + (j & 7)] = bf16r(acc * scale);
        }
        if (ag == 3) wf16[((j >> 3) * 16 + 6) * 8 + (j & 7)] = bf16r(1.0f);  // ones col
        for (int a7 = 7 + ag; a7 < 16; a7 += 4)
            wf16[((j >> 3) * 16 + a7) * 8 + (j & 7)] = 0;
    }
    if (jt == 0) {
        __syncthreads();
        if (t < NA) {
            float acc = 0.f;
            for (int e = 0; e < NE; ++e) acc = fmaf(b2[e], WqK[e * 8 + t], acc);
            ws[OFF_BATTN + t] = acc * scale;
        }
        if (t < 64) ws[OFF_S + t] = 0.f;
    }
}

// ---------------------------------------------------------------- A:
// per (bt,n): GEMM1 (MFMA, frag loads fully coalesced): hT = We2^T @ x^T,
// relu+bias; GEMM2 (MFMA): attnT[a][b] (ones col -> hsum). ARAW [b][n][8].
__global__ __launch_bounds__(256) void kA(float* __restrict__ ws) {
    const int bt = blockIdx.x, n = blockIdx.y;
    const int t = threadIdx.x, w = t >> 6, l = t & 63, lo = l & 15, hi = l >> 4;
    const int j0 = w * 64;
    __shared__ float be2s[256];
    __shared__ float red[4][16][64];

    be2s[t] = ws[OFF_BE2 + n * NH + t];

    const short8* Af = (const short8*)(ws + OFF_WE2F);
    const short8* Bf = (const short8*)(ws + OFF_XBF);
    short8 afr[4][2], bfr[4][2];
    #pragma unroll
    for (int mf = 0; mf < 4; ++mf)
        #pragma unroll
        for (int kk = 0; kk < 2; ++kk)
            afr[mf][kk] = Af[(((size_t)n * 4 + w) * 4 + mf) * 2 * 64 + (size_t)kk * 64 + l];
    #pragma unroll
    for (int nf = 0; nf < 4; ++nf)
        #pragma unroll
        for (int kk = 0; kk < 2; ++kk)
            bfr[nf][kk] = Bf[(((size_t)bt * 4 + nf) * 2 + kk) * 64 + l];

    f32x4 zero = {0.f, 0.f, 0.f, 0.f};
    f32x4 acc[4][4];
    #pragma unroll
    for (int mf = 0; mf < 4; ++mf)
        #pragma unroll
        for (int nf = 0; nf < 4; ++nf) acc[mf][nf] = zero;

    #pragma unroll
    for (int kk = 0; kk < 2; ++kk)
        #pragma unroll
        for (int mf = 0; mf < 4; ++mf)
            #pragma unroll
            for (int nf = 0; nf < 4; ++nf)
                acc[mf][nf] = __builtin_amdgcn_mfma_f32_16x16x32_bf16(
                    afr[mf][kk], bfr[nf][kk], acc[mf][nf], 0, 0, 0);

    __syncthreads();   // be2s ready

    // h = relu(acc + be2[j]); pack bf16. lane: row j = j0+mf*16+hi*4+i, col b = nf*16+lo
    unsigned P[4][4][2];
    #pragma unroll
    for (int mf = 0; mf < 4; ++mf) {
        const int jb = j0 + mf * 16 + hi * 4;
        #pragma unroll
        for (int nf = 0; nf < 4; ++nf) {
            float h0 = fmaxf(acc[mf][nf][0] + be2s[jb + 0], 0.f);
            float h1 = fmaxf(acc[mf][nf][1] + be2s[jb + 1], 0.f);
            float h2 = fmaxf(acc[mf][nf][2] + be2s[jb + 2], 0.f);
            float h3 = fmaxf(acc[mf][nf][3] + be2s[jb + 3], 0.f);
            P[mf][nf][0] = bfpack(h0, h1);
            P[mf][nf][1] = bfpack(h2, h3);
        }
    }

    // GEMM2: attnT[a16][b64] over this wave's 64 j's (K=64 -> 2 steps of 32)
    const short8* Wf = (const short8*)(ws + OFF_WATTNF);
    f32x4 acc2[4];
    #pragma unroll
    for (int nf = 0; nf < 4; ++nf) acc2[nf] = zero;
    #pragma unroll
    for (int kk2 = 0; kk2 < 2; ++kk2) {
        short8 a2 = Wf[(size_t)(w * 2 + kk2) * 64 + l];
        #pragma unroll
        for (int nf = 0; nf < 4; ++nf) {
            unsigned bq[4];
            #pragma unroll
            for (int q = 0; q < 4; ++q) {
                int s = ((hi & 1) * 2 + (q >> 1)) * 16 + lo;
                unsigned vA = (unsigned)__shfl((int)P[2 * kk2 + 0][nf][q & 1], s, 64);
                unsigned vB = (unsigned)__shfl((int)P[2 * kk2 + 1][nf][q & 1], s, 64);
                bq[q] = (hi >= 2) ? vB : vA;
            }
            union { unsigned u[4]; short8 v; } cv;
            cv.u[0] = bq[0]; cv.u[1] = bq[1]; cv.u[2] = bq[2]; cv.u[3] = bq[3];
            acc2[nf] = __builtin_amdgcn_mfma_f32_16x16x32_bf16(a2, cv.v, acc2[nf], 0, 0, 0);
        }
    }

    // cross-wave reduce
    #pragma unroll
    for (int nf = 0; nf < 4; ++nf)
        #pragma unroll
        for (int i = 0; i < 4; ++i)
            red[w][hi * 4 + i][nf * 16 + lo] = acc2[nf][i];
    __syncthreads();

    const int rb = t & 63, a0 = t >> 6, a1 = a0 + 4;
    float v0 = red[0][a0][rb] + red[1][a0][rb] + red[2][a0][rb] + red[3][a0][rb];
    float v1 = red[0][a1][rb] + red[1][a1][rb] + red[2][a1][rb] + red[3][a1][rb];
    if (a1 == 6) {   // wave 2: ones-column = h row-sums -> global S[n]
        float hs = v1;
        #pragma unroll
        for (int m = 1; m < 64; m <<= 1) hs += __shfl_xor(hs, m, 64);
        if (l == 0) atomicAdd(ws + OFF_S + n, hs);
    }
    __syncthreads();                       // done reading red
    float* red2 = &red[0][0][0];           // [64 b][8 a]
    red2[rb * 8 + a0] = v0;
    red2[rb * 8 + a1] = v1;
    __syncthreads();
    if (t < 128) {                         // ARAW[b][n][8]
        int i = t >> 1, half = t & 1;
        float4 v = *(const float4*)&red2[i * 8 + half * 4];
        *(float4*)(ws + OFF_ARAW + ((size_t)(bt * 64 + i) * 64 + n) * 8 + half * 4) = v;
    }
}

// ---------------------------------------------------------------- C:
// block = one batch row b: thread0 scalar gate chain (c), contiguous 2 KB
// ARAW read via LDS, softmax(6) per token, 32 KB contiguous output write.
__global__ __launch_bounds__(256) void kC(const float* __restrict__ ws,
                                          const float* __restrict__ basis,
                                          const float* __restrict__ mW1, const float* __restrict__ mb1,
                                          const float* __restrict__ mW2, const float* __restrict__ mb2,
                                          const float* __restrict__ gW1, const float* __restrict__ gb1,
                                          const float* __restrict__ gW2, const float* __restrict__ gb2,
                                          float* __restrict__ out) {
    const int b = blockIdx.x;
    const int t = threadIdx.x;
    __shared__ float ars[512];
    __shared__ float sw[64][8];
    __shared__ float bs[6][128];
    __shared__ float csh;
    if (t < 128)
        ((float4*)ars)[t] = ((const float4*)(ws + OFF_ARAW + (size_t)b * 512))[t];
    for (int q = t; q < NA * NE; q += 256) bs[q >> 7][q & 127] = basis[q];
    if (t == 0) {   // scalar gate chain
        float S = 0.f;
        for (int i = 0; i < 64; ++i) S += ws[OFF_S + i];
        float s = S / ((float)NB * NN * NH);
        float accm = mb2[0];
        for (int i = 0; i < 8; ++i) accm += fmaxf(s * mW1[i] + mb1[i], 0.f) * mW2[i];
        float m = 1.f / (1.f + expf(-accm));
        float state = 0.9f * 0.5f + 0.1f * m;
        float c1 = 1.f + 0.1f * (state - 0.5f);
        float sg = c1 * s;
        float accg = gb2[0];
        for (int i = 0; i < 16; ++i) accg += fmaxf(sg * gW1[i] + gb1[i], 0.f) * gW2[i];
        float g = 1.f / (1.f + expf(-accg));
        csh = c1 * g;
    }
    __syncthreads();
    if (t < 64) {
        const float c = csh;
        float at[6], mx = -1e30f;
        #pragma unroll
        for (int a = 0; a < 6; ++a) {
            at[a] = fmaf(c, ars[t * 8 + a], ws[OFF_BATTN + a]);
            mx = fmaxf(mx, at[a]);
        }
        float ex[6], ssum = 0.f;
        #pragma unroll
        for (int a = 0; a < 6; ++a) { ex[a] = expf(at[a] - mx); ssum += ex[a]; }
        float inv = 1.f / ssum;
        #pragma unroll
        for (int a = 0; a < 6; ++a) sw[t][a] = ex[a] * inv;
    }
    __syncthreads();
    float* op = out + (size_t)b * (NN * NE);
    #pragma unroll
    for (int i = 0; i < 8; ++i) {
        int idx = i * 1024 + t * 4;          // 0..8191
        int n = idx >> 7, e = idx & 127;
        float wv[6];
        #pragma unroll
        for (int a = 0; a < 6; ++a) wv[a] = sw[n][a];
        float4 r;
        #pragma unroll
        for (int cc = 0; cc < 4; ++cc) {
            float o = 0.f;
            #pragma unroll
            for (int a = 0; a < 6; ++a) o = fmaf(wv[a], bs[a][e + cc], o);
            ((float*)&r)[cc] = fminf(fmaxf(o, -3.f), 3.f);
        }
        *(float4*)(op + idx) = r;
    }
}

extern "C" void kernel_launch(void* const* d_in, const int* in_sizes, int n_in,
                              void* d_out, int out_size, void* d_ws, size_t ws_size,
                              hipStream_t stream) {
    const float* x     = (const float*)d_in[0];
    const float* Wemb  = (const float*)d_in[1];
    const float* bemb  = (const float*)d_in[2];
    const float* adjw  = (const float*)d_in[3];
    const float* W1    = (const float*)d_in[4];
    const float* b1    = (const float*)d_in[5];
    const float* W2    = (const float*)d_in[6];
    const float* b2    = (const float*)d_in[7];
    const float* basis = (const float*)d_in[8];
    const float* Wq    = (const float*)d_in[9];
    const float* Wk    = (const float*)d_in[10];
    const float* mW1   = (const float*)d_in[11];
    const float* mb1   = (const float*)d_in[12];
    const float* mW2   = (const float*)d_in[13];
    const float* mb2   = (const float*)d_in[14];
    const float* gW1   = (const float*)d_in[15];
    const float* gb1   = (const float*)d_in[16];
    const float* gW2   = (const float*)d_in[17];
    const float* gb2   = (const float*)d_in[18];
    float* ws  = (float*)d_ws;
    float* out = (float*)d_out;

    kP<<<324, 512, 0, stream>>>(x, Wemb, bemb, adjw, W1, b1, basis, Wq, Wk, W2, b2, ws);
    kA<<<dim3(64, 64), 256, 0, stream>>>(ws);
    kC<<<NB, 256, 0, stream>>>(ws, basis, mW1, mb1, mW2, mb2, gW1, gb1, gW2, gb2, out);
}

// Round 14
// 98.004 us; speedup vs baseline: 1.3743x; 1.2185x over previous
//
#include <hip/hip_runtime.h>
#include <math.h>

#define NN 64      // nodes
#define NF 64      // input features (= K of main GEMM)
#define NE 128     // embed
#define NH 256     // hidden
#define NA 6       // atoms
#define NB 4096    // batch
#define NT (NB*NN) // tokens = 262144

// ---- workspace layout (float offsets) ----
#define OFF_WATTN16 8192u     // 2048 fl (reserved, unused)
#define OFF_BE2    20480u     // 64*256 fp32
#define OFF_BATTN  36864u     // 6 (pad 8)
#define OFF_S      36872u     // 64
#define OFF_WATTNF 36944u     // 2048 fl = 4096 bf16 (GEMM2 A-frag: [j>>3][a16][j&7])
#define OFF_XBF    38992u     // 131072 fl = x bf16 in B-frag order [bt][nf][kk][l][8]
#define OFF_WE2F   170064u    // 2097152 fl = We2 bf16 in A-frag order [n][w][mf][kk][l][8]
#define OFF_ARAW   2267216u   // 2097152 fl = [b][n][8]
// end 4364368 floats = 17.5 MB

typedef __attribute__((ext_vector_type(8))) short short8;
typedef __attribute__((ext_vector_type(4))) float f32x4;
typedef __attribute__((ext_vector_type(4))) unsigned short us4;

static __device__ __forceinline__ unsigned short bf16r(float f) {
    unsigned u = __float_as_uint(f);
    return (unsigned short)((u + 0x7FFFu + ((u >> 16) & 1u)) >> 16);
}
static __device__ __forceinline__ unsigned bfpack(float lo, float hi) {
    return (unsigned)bf16r(lo) | ((unsigned)bf16r(hi) << 16);
}

// ---------------------------------------------------------------- kP (fused prep, 512 thr):
// bx 0..255   : (n = bx>>2, jq = bx&3) We2 GEMM -> frag-order bf16 + be2 fp32
// bx 256..319 : x -> bf16 in B-frag order
// bx 320..323 : Wattn (jt) -> frag layouts; jt==0 also battn + zero S
__global__ __launch_bounds__(512) void kP(
        const float* __restrict__ x, const float* __restrict__ Wemb,
        const float* __restrict__ bemb, const float* __restrict__ adjw,
        const float* __restrict__ W1, const float* __restrict__ b1,
        const float* __restrict__ basis, const float* __restrict__ Wq,
        const float* __restrict__ Wk, const float* __restrict__ W2,
        const float* __restrict__ b2, float* __restrict__ ws) {
    __shared__ float sh[17024];
    const int bx = blockIdx.x, t = threadIdx.x;

    if (bx < 256) {
        // ---- We2 GEMM block: n, j-quarter (64 j x 64 f, K=128) ----
        const int n = bx >> 2, jq = bx & 3;
        float* WmT = sh;              // [128 e][68]  (transposed mix, padded)
        float* W1q = sh + 8704;       // [128 e][64 j]
        float* bm  = sh + 16896;      // [128 e]
        const int r = n >> 3, c = n & 7;
        int ml[4]; int nm = 0;
        if (r > 0) ml[nm++] = n - 8;
        if (r < 7) ml[nm++] = n + 8;
        if (c > 0) ml[nm++] = n - 1;
        if (c < 7) ml[nm++] = n + 1;
        float av[4]; float asum = 0.f;
        for (int d = 0; d < nm; ++d) {
            av[d] = 1.f / (1.f + expf(-adjw[n * NN + ml[d]]));
            asum += av[d];
        }
        const float ainv = 1.f / fmaxf(asum, 1e-6f);
        for (int d = 0; d < nm; ++d) av[d] *= ainv;

        #pragma unroll 4
        for (int i = 0; i < 16; ++i) {              // WmT[e][f]
            int idx = i * 512 + t;
            int f = idx >> 7, e = idx & 127;
            float acc = 0.f;
            for (int d = 0; d < nm; ++d)
                acc = fmaf(av[d], Wemb[(size_t)f * (NN * NE) + ml[d] * NE + e], acc);
            WmT[e * 68 + f] = acc;
        }
        if (t < 128) {
            float accb = 0.f;
            for (int d = 0; d < nm; ++d)
                accb = fmaf(av[d], bemb[ml[d] * NE + t], accb);
            bm[t] = accb;
        }
        #pragma unroll 4
        for (int i = 0; i < 16; ++i) {              // W1q[e][j]
            int idx = i * 512 + t;
            int e = idx >> 6, j6 = idx & 63;
            W1q[e * 64 + j6] = W1[(size_t)e * NH + jq * 64 + j6];
        }
        __syncthreads();

        const int jg = t & 15, fg = t >> 4;         // j-quad, f-pair
        float acc[4][2];
        #pragma unroll
        for (int jj = 0; jj < 4; ++jj) { acc[jj][0] = 0.f; acc[jj][1] = 0.f; }
        float accb[4] = {0.f, 0.f, 0.f, 0.f};
        #pragma unroll 4
        for (int e = 0; e < 128; ++e) {
            float4 w1 = *(const float4*)&W1q[e * 64 + jg * 4];
            float2 wm = *(const float2*)&WmT[e * 68 + fg * 2];
            const float w1v[4] = {w1.x, w1.y, w1.z, w1.w};
            #pragma unroll
            for (int jj = 0; jj < 4; ++jj) {
                acc[jj][0] = fmaf(w1v[jj], wm.x, acc[jj][0]);
                acc[jj][1] = fmaf(w1v[jj], wm.y, acc[jj][1]);
            }
            if (fg == 0) {
                float bb = bm[e];
                #pragma unroll
                for (int jj = 0; jj < 4; ++jj) accb[jj] = fmaf(bb, w1v[jj], accb[jj]);
            }
        }
        // frag-order write: f-pair (e0, e0+1) of chunk (n, jq, mf, kk) lane (hi,lo)
        unsigned short* wf = (unsigned short*)(ws + OFF_WE2F);
        const int mfj = jg >> 2, kk = fg >> 4;
        const int lbase = ((fg >> 2) & 3) * 16, e0 = (fg & 3) * 2;
        const size_t cb = ((((size_t)n * 4 + jq) * 4 + mfj) * 2 + kk) * 64;
        #pragma unroll
        for (int jj = 0; jj < 4; ++jj) {
            int l16 = (jg * 4 + jj) & 15;
            *(unsigned*)(wf + (cb + lbase + l16) * 8 + e0) = bfpack(acc[jj][0], acc[jj][1]);
        }
        if (fg == 0) {
            #pragma unroll
            for (int jj = 0; jj < 4; ++jj) {
                int j = jq * 64 + jg * 4 + jj;
                ws[OFF_BE2 + n * NH + j] = accb[jj] + b1[j];
            }
        }
        return;
    }
    if (bx < 320) {
        // ---- x -> bf16 B-frag order ----
        int g = (bx - 256) * 512 + t;               // 0..32767
        int b = g >> 3, ko = g & 7;
        float4 v0 = ((const float4*)x)[b * 16 + ko * 2];
        float4 v1 = ((const float4*)x)[b * 16 + ko * 2 + 1];
        union { unsigned u[4]; short8 v; } cv;
        cv.u[0] = bfpack(v0.x, v0.y); cv.u[1] = bfpack(v0.z, v0.w);
        cv.u[2] = bfpack(v1.x, v1.y); cv.u[3] = bfpack(v1.z, v1.w);
        int bt = b >> 6, nf = (b >> 4) & 3, kk = ko >> 2, l = (ko & 3) * 16 + (b & 15);
        ((short8*)(ws + OFF_XBF))[(((size_t)bt * 4 + nf) * 2 + kk) * 64 + l] = cv.v;
        return;
    }
    // ---- Wattn blocks: jt = bx-320 handles j = jt*64..+63 ----
    const int jt = bx - 320;
    float* Ks  = sh;            // [6][128]
    float* WqK = sh + 768;      // [128][8] (pad)
    float* W2t = sh + 1792;     // [64][129]
    for (int q = t; q < NA * NE; q += 512) {
        int a = q >> 7, e2 = q & 127;
        float acc = 0.f;
        for (int e = 0; e < NE; ++e) acc = fmaf(basis[a * NE + e], Wk[e * NE + e2], acc);
        Ks[a * NE + e2] = acc;
    }
    __syncthreads();
    for (int q = t; q < NE * NA; q += 512) {
        int e = q / NA, a = q - e * NA;
        float acc = 0.f;
        for (int e2 = 0; e2 < NE; ++e2) acc = fmaf(Wq[e * NE + e2], Ks[a * NE + e2], acc);
        WqK[e * 8 + a] = acc;
    }
    __syncthreads();
    for (int i = 0; i < 16; ++i) {                  // stage W2 rows jt*64..+63
        int idx = i * 512 + t;
        int jr = idx >> 7, e = idx & 127;
        W2t[jr * 129 + e] = W2[(size_t)(jt * 64 + jr) * NE + e];
    }
    __syncthreads();
    const float scale = 1.f / (sqrtf(128.f) + 1e-8f);
    unsigned short* wf16 = (unsigned short*)(ws + OFF_WATTNF);
    if (t < 256) {
        const int jl = t & 63, ag = t >> 6;
        const int j = jt * 64 + jl;
        const int na = (ag < 2) ? 2 : 1;
        for (int ai = 0; ai < na; ++ai) {
            int a = ag + ai * 4;
            float acc = 0.f;
            for (int e = 0; e < NE; ++e)
                acc = fmaf(W2t[jl * 129 + e], WqK[e * 8 + a], acc);
            wf16[((j >> 3) * 16 + a) * 8 + (j & 7)] = bf16r(acc * scale);
        }
        if (ag == 3) wf16[((j >> 3) * 16 + 6) * 8 + (j & 7)] = bf16r(1.0f);  // ones col
        for (int a7 = 7 + ag; a7 < 16; a7 += 4)
            wf16[((j >> 3) * 16 + a7) * 8 + (j & 7)] = 0;
    }
    if (jt == 0) {
        __syncthreads();
        if (t < NA) {
            float acc = 0.f;
            for (int e = 0; e < NE; ++e) acc = fmaf(b2[e], WqK[e * 8 + t], acc);
            ws[OFF_BATTN + t] = acc * scale;
        }
        if (t < 64) ws[OFF_S + t] = 0.f;
    }
}

// ---------------------------------------------------------------- A:
// block = (g, n): afr/wfr/be2s loaded ONCE, loop over 8 bt tiles with register
// prefetch. GEMM1 (MFMA) -> relu+bias -> shuffle GEMM2 (proven path).
// Race audit (per-iteration, 2 barriers B1/B2):
//   red  W(iter k+1, pre-B1) vs red  R(iter k, B1..B2)   -> ordered by B2(k)
//   red2 W(iter k+1, B1..B2) vs red2 R(iter k, post-B2)  -> ordered by B1(k+1)
__global__ __launch_bounds__(256) void kA(float* __restrict__ ws) {
    const int g = blockIdx.x, n = blockIdx.y;     // g: 0..7, each covers 8 bt
    const int t = threadIdx.x, w = t >> 6, l = t & 63, lo = l & 15, hi = l >> 4;
    const int j0 = w * 64;
    __shared__ float be2s[256];
    __shared__ float red[4][16][64];
    __shared__ float red2[512];

    be2s[t] = ws[OFF_BE2 + n * NH + t];

    const short8* Af = (const short8*)(ws + OFF_WE2F);
    const short8* Bf = (const short8*)(ws + OFF_XBF);
    const short8* Wf = (const short8*)(ws + OFF_WATTNF);
    short8 afr[4][2];
    #pragma unroll
    for (int mf = 0; mf < 4; ++mf)
        #pragma unroll
        for (int kk = 0; kk < 2; ++kk)
            afr[mf][kk] = Af[(((size_t)n * 4 + w) * 4 + mf) * 128 + (size_t)kk * 64 + l];
    short8 wfr8[2];
    #pragma unroll
    for (int kk2 = 0; kk2 < 2; ++kk2)
        wfr8[kk2] = Wf[(size_t)(w * 2 + kk2) * 64 + l];

    f32x4 zero = {0.f, 0.f, 0.f, 0.f};
    short8 bcur[4][2], bnxt[4][2];
    #pragma unroll
    for (int nf = 0; nf < 4; ++nf)
        #pragma unroll
        for (int kk = 0; kk < 2; ++kk)
            bcur[nf][kk] = Bf[(((size_t)(g * 8) * 4 + nf) * 2 + kk) * 64 + l];
    float hsacc = 0.f;
    __syncthreads();   // be2s ready

    for (int it = 0; it < 8; ++it) {
        const int bt = g * 8 + it;
        if (it < 7) {   // prefetch next B tile; lands during GEMM1+epilogue
            #pragma unroll
            for (int nf = 0; nf < 4; ++nf)
                #pragma unroll
                for (int kk = 0; kk < 2; ++kk)
                    bnxt[nf][kk] = Bf[(((size_t)(bt + 1) * 4 + nf) * 2 + kk) * 64 + l];
        }

        f32x4 acc[4][4];
        #pragma unroll
        for (int mf = 0; mf < 4; ++mf)
            #pragma unroll
            for (int nf = 0; nf < 4; ++nf) acc[mf][nf] = zero;
        #pragma unroll
        for (int kk = 0; kk < 2; ++kk)
            #pragma unroll
            for (int mf = 0; mf < 4; ++mf)
                #pragma unroll
                for (int nf = 0; nf < 4; ++nf)
                    acc[mf][nf] = __builtin_amdgcn_mfma_f32_16x16x32_bf16(
                        afr[mf][kk], bcur[nf][kk], acc[mf][nf], 0, 0, 0);

        // GEMM2 per kk2: pack only the two mf's it needs (16 P regs live)
        f32x4 acc2[4];
        #pragma unroll
        for (int nf = 0; nf < 4; ++nf) acc2[nf] = zero;
        #pragma unroll
        for (int kk2 = 0; kk2 < 2; ++kk2) {
            unsigned P2[2][4][2];
            #pragma unroll
            for (int dm = 0; dm < 2; ++dm) {
                const int mf = kk2 * 2 + dm;
                const int jb = j0 + mf * 16 + hi * 4;
                #pragma unroll
                for (int nf = 0; nf < 4; ++nf) {
                    float h0 = fmaxf(acc[mf][nf][0] + be2s[jb + 0], 0.f);
                    float h1 = fmaxf(acc[mf][nf][1] + be2s[jb + 1], 0.f);
                    float h2 = fmaxf(acc[mf][nf][2] + be2s[jb + 2], 0.f);
                    float h3 = fmaxf(acc[mf][nf][3] + be2s[jb + 3], 0.f);
                    P2[dm][nf][0] = bfpack(h0, h1);
                    P2[dm][nf][1] = bfpack(h2, h3);
                }
            }
            #pragma unroll
            for (int nf = 0; nf < 4; ++nf) {
                unsigned bq[4];
                #pragma unroll
                for (int q = 0; q < 4; ++q) {
                    int s = ((hi & 1) * 2 + (q >> 1)) * 16 + lo;
                    unsigned vA = (unsigned)__shfl((int)P2[0][nf][q & 1], s, 64);
                    unsigned vB = (unsigned)__shfl((int)P2[1][nf][q & 1], s, 64);
                    bq[q] = (hi >= 2) ? vB : vA;
                }
                union { unsigned u[4]; short8 v; } cv;
                cv.u[0] = bq[0]; cv.u[1] = bq[1]; cv.u[2] = bq[2]; cv.u[3] = bq[3];
                acc2[nf] = __builtin_amdgcn_mfma_f32_16x16x32_bf16(wfr8[kk2], cv.v, acc2[nf], 0, 0, 0);
            }
        }

        // cross-wave reduce
        #pragma unroll
        for (int nf = 0; nf < 4; ++nf)
            #pragma unroll
            for (int i = 0; i < 4; ++i)
                red[w][hi * 4 + i][nf * 16 + lo] = acc2[nf][i];
        __syncthreads();                                   // B1

        const int rb = t & 63, a0 = t >> 6, a1 = a0 + 4;
        float v0 = red[0][a0][rb] + red[1][a0][rb] + red[2][a0][rb] + red[3][a0][rb];
        float v1 = red[0][a1][rb] + red[1][a1][rb] + red[2][a1][rb] + red[3][a1][rb];
        red2[rb * 8 + a0] = v0;
        red2[rb * 8 + a1] = v1;
        if (a1 == 6) {   // wave 2: ones-column = h row-sums
            float hs = v1;
            #pragma unroll
            for (int m = 1; m < 64; m <<= 1) hs += __shfl_xor(hs, m, 64);
            if (l == 0) hsacc += hs;
        }
        __syncthreads();                                   // B2
        if (t < 128) {                         // ARAW[b][n][8]
            int i = t >> 1, half = t & 1;
            float4 v = *(const float4*)&red2[i * 8 + half * 4];
            *(float4*)(ws + OFF_ARAW + ((size_t)(bt * 64 + i) * 64 + n) * 8 + half * 4) = v;
        }
        if (it < 7) {
            #pragma unroll
            for (int nf = 0; nf < 4; ++nf)
                #pragma unroll
                for (int kk = 0; kk < 2; ++kk)
                    bcur[nf][kk] = bnxt[nf][kk];
        }
    }

    if (w == 2 && l == 0) atomicAdd(ws + OFF_S + n, hsacc);
}

// ---------------------------------------------------------------- C:
// block = one batch row b: thread0 scalar gate chain (c), contiguous 2 KB
// ARAW read via LDS, softmax(6) per token, 32 KB contiguous output write.
__global__ __launch_bounds__(256) void kC(const float* __restrict__ ws,
                                          const float* __restrict__ basis,
                                          const float* __restrict__ mW1, const float* __restrict__ mb1,
                                          const float* __restrict__ mW2, const float* __restrict__ mb2,
                                          const float* __restrict__ gW1, const float* __restrict__ gb1,
                                          const float* __restrict__ gW2, const float* __restrict__ gb2,
                                          float* __restrict__ out) {
    const int b = blockIdx.x;
    const int t = threadIdx.x;
    __shared__ float ars[512];
    __shared__ float sw[64][8];
    __shared__ float bs[6][128];
    __shared__ float csh;
    if (t < 128)
        ((float4*)ars)[t] = ((const float4*)(ws + OFF_ARAW + (size_t)b * 512))[t];
    for (int q = t; q < NA * NE; q += 256) bs[q >> 7][q & 127] = basis[q];
    if (t == 0) {   // scalar gate chain
        float S = 0.f;
        for (int i = 0; i < 64; ++i) S += ws[OFF_S + i];
        float s = S / ((float)NB * NN * NH);
        float accm = mb2[0];
        for (int i = 0; i < 8; ++i) accm += fmaxf(s * mW1[i] + mb1[i], 0.f) * mW2[i];
        float m = 1.f / (1.f + expf(-accm));
        float state = 0.9f * 0.5f + 0.1f * m;
        float c1 = 1.f + 0.1f * (state - 0.5f);
        float sg = c1 * s;
        float accg = gb2[0];
        for (int i = 0; i < 16; ++i) accg += fmaxf(sg * gW1[i] + gb1[i], 0.f) * gW2[i];
        float g = 1.f / (1.f + expf(-accg));
        csh = c1 * g;
    }
    __syncthreads();
    if (t < 64) {
        const float c = csh;
        float at[6], mx = -1e30f;
        #pragma unroll
        for (int a = 0; a < 6; ++a) {
            at[a] = fmaf(c, ars[t * 8 + a], ws[OFF_BATTN + a]);
            mx = fmaxf(mx, at[a]);
        }
        float ex[6], ssum = 0.f;
        #pragma unroll
        for (int a = 0; a < 6; ++a) { ex[a] = expf(at[a] - mx); ssum += ex[a]; }
        float inv = 1.f / ssum;
        #pragma unroll
        for (int a = 0; a < 6; ++a) sw[t][a] = ex[a] * inv;
    }
    __syncthreads();
    float* op = out + (size_t)b * (NN * NE);
    #pragma unroll
    for (int i = 0; i < 8; ++i) {
        int idx = i * 1024 + t * 4;          // 0..8191
        int n = idx >> 7, e = idx & 127;
        float wv[6];
        #pragma unroll
        for (int a = 0; a < 6; ++a) wv[a] = sw[n][a];
        float4 r;
        #pragma unroll
        for (int cc = 0; cc < 4; ++cc) {
            float o = 0.f;
            #pragma unroll
            for (int a = 0; a < 6; ++a) o = fmaf(wv[a], bs[a][e + cc], o);
            ((float*)&r)[cc] = fminf(fmaxf(o, -3.f), 3.f);
        }
        *(float4*)(op + idx) = r;
    }
}

extern "C" void kernel_launch(void* const* d_in, const int* in_sizes, int n_in,
                              void* d_out, int out_size, void* d_ws, size_t ws_size,
                              hipStream_t stream) {
    const float* x     = (const float*)d_in[0];
    const float* Wemb  = (const float*)d_in[1];
    const float* bemb  = (const float*)d_in[2];
    const float* adjw  = (const float*)d_in[3];
    const float* W1    = (const float*)d_in[4];
    const float* b1    = (const float*)d_in[5];
    const float* W2    = (const float*)d_in[6];
    const float* b2    = (const float*)d_in[7];
    const float* basis = (const float*)d_in[8];
    const float* Wq    = (const float*)d_in[9];
    const float* Wk    = (const float*)d_in[10];
    const float* mW1   = (const float*)d_in[11];
    const float* mb1   = (const float*)d_in[12];
    const float* mW2   = (const float*)d_in[13];
    const float* mb2   = (const float*)d_in[14];
    const float* gW1   = (const float*)d_in[15];
    const float* gb1   = (const float*)d_in[16];
    const float* gW2   = (const float*)d_in[17];
    const float* gb2   = (const float*)d_in[18];
    float* ws  = (float*)d_ws;
    float* out = (float*)d_out;

    kP<<<324, 512, 0, stream>>>(x, Wemb, bemb, adjw, W1, b1, basis, Wq, Wk, W2, b2, ws);
    kA<<<dim3(8, 64), 256, 0, stream>>>(ws);
    kC<<<NB, 256, 0, stream>>>(ws, basis, mW1, mb1, mW2, mb2, gW1, gb1, gW2, gb2, out);
}

// Round 15
// 97.466 us; speedup vs baseline: 1.3819x; 1.0055x over previous
//
#include <hip/hip_runtime.h>
#include <math.h>

#define NN 64      // nodes
#define NF 64      // input features (= K of main GEMM)
#define NE 128     // embed
#define NH 256     // hidden
#define NA 6       // atoms
#define NB 4096    // batch
#define NT (NB*NN) // tokens = 262144

// ---- workspace layout (float offsets) ----
#define OFF_WATTN16 8192u     // 2048 fl (reserved, unused)
#define OFF_BE2    20480u     // 64*256 fp32
#define OFF_BATTN  36864u     // 6 (pad 8)
#define OFF_S      36872u     // 64
#define OFF_WATTNF 36944u     // 2048 fl = 4096 bf16 (GEMM2 A-frag: [j>>3][a16][j&7])
#define OFF_XBF    38992u     // 131072 fl = x bf16 in B-frag order [bt][nf][kk][l][8]
#define OFF_WE2F   170064u    // 2097152 fl = We2 bf16 in A-frag order [n][w][mf][kk][l][8]
#define OFF_ARAW   2267216u   // 2097152 fl = [b][n][8]
// end 4364368 floats = 17.5 MB

typedef __attribute__((ext_vector_type(8))) short short8;
typedef __attribute__((ext_vector_type(4))) float f32x4;
typedef __attribute__((ext_vector_type(4))) unsigned short us4;

static __device__ __forceinline__ unsigned short bf16r(float f) {
    unsigned u = __float_as_uint(f);
    return (unsigned short)((u + 0x7FFFu + ((u >> 16) & 1u)) >> 16);
}
static __device__ __forceinline__ unsigned bfpack(float lo, float hi) {
    return (unsigned)bf16r(lo) | ((unsigned)bf16r(hi) << 16);
}

// ---------------------------------------------------------------- kP (fused prep, 512 thr):
// bx 0..255   : (n = bx>>2, jq = bx&3) We2 GEMM -> frag-order bf16 + be2 fp32
// bx 256..319 : x -> bf16 in B-frag order
// bx 320..323 : Wattn (jt) -> frag layouts; jt==0 also battn + zero S
__global__ __launch_bounds__(512) void kP(
        const float* __restrict__ x, const float* __restrict__ Wemb,
        const float* __restrict__ bemb, const float* __restrict__ adjw,
        const float* __restrict__ W1, const float* __restrict__ b1,
        const float* __restrict__ basis, const float* __restrict__ Wq,
        const float* __restrict__ Wk, const float* __restrict__ W2,
        const float* __restrict__ b2, float* __restrict__ ws) {
    __shared__ float sh[17024];
    const int bx = blockIdx.x, t = threadIdx.x;

    if (bx < 256) {
        // ---- We2 GEMM block: n, j-quarter (64 j x 64 f, K=128) ----
        const int n = bx >> 2, jq = bx & 3;
        float* WmT = sh;              // [128 e][68]  (transposed mix, padded)
        float* W1q = sh + 8704;       // [128 e][64 j]
        float* bm  = sh + 16896;      // [128 e]
        const int r = n >> 3, c = n & 7;
        int ml[4]; int nm = 0;
        if (r > 0) ml[nm++] = n - 8;
        if (r < 7) ml[nm++] = n + 8;
        if (c > 0) ml[nm++] = n - 1;
        if (c < 7) ml[nm++] = n + 1;
        float av[4]; float asum = 0.f;
        for (int d = 0; d < nm; ++d) {
            av[d] = 1.f / (1.f + expf(-adjw[n * NN + ml[d]]));
            asum += av[d];
        }
        const float ainv = 1.f / fmaxf(asum, 1e-6f);
        for (int d = 0; d < nm; ++d) av[d] *= ainv;

        #pragma unroll 4
        for (int i = 0; i < 16; ++i) {              // WmT[e][f]
            int idx = i * 512 + t;
            int f = idx >> 7, e = idx & 127;
            float acc = 0.f;
            for (int d = 0; d < nm; ++d)
                acc = fmaf(av[d], Wemb[(size_t)f * (NN * NE) + ml[d] * NE + e], acc);
            WmT[e * 68 + f] = acc;
        }
        if (t < 128) {
            float accb = 0.f;
            for (int d = 0; d < nm; ++d)
                accb = fmaf(av[d], bemb[ml[d] * NE + t], accb);
            bm[t] = accb;
        }
        #pragma unroll 4
        for (int i = 0; i < 16; ++i) {              // W1q[e][j]
            int idx = i * 512 + t;
            int e = idx >> 6, j6 = idx & 63;
            W1q[e * 64 + j6] = W1[(size_t)e * NH + jq * 64 + j6];
        }
        __syncthreads();

        const int jg = t & 15, fg = t >> 4;         // j-quad, f-pair
        float acc[4][2];
        #pragma unroll
        for (int jj = 0; jj < 4; ++jj) { acc[jj][0] = 0.f; acc[jj][1] = 0.f; }
        float accb[4] = {0.f, 0.f, 0.f, 0.f};
        #pragma unroll 4
        for (int e = 0; e < 128; ++e) {
            float4 w1 = *(const float4*)&W1q[e * 64 + jg * 4];
            float2 wm = *(const float2*)&WmT[e * 68 + fg * 2];
            const float w1v[4] = {w1.x, w1.y, w1.z, w1.w};
            #pragma unroll
            for (int jj = 0; jj < 4; ++jj) {
                acc[jj][0] = fmaf(w1v[jj], wm.x, acc[jj][0]);
                acc[jj][1] = fmaf(w1v[jj], wm.y, acc[jj][1]);
            }
            if (fg == 0) {
                float bb = bm[e];
                #pragma unroll
                for (int jj = 0; jj < 4; ++jj) accb[jj] = fmaf(bb, w1v[jj], accb[jj]);
            }
        }
        // frag-order write: f-pair (e0, e0+1) of chunk (n, jq, mf, kk) lane (hi,lo)
        unsigned short* wf = (unsigned short*)(ws + OFF_WE2F);
        const int mfj = jg >> 2, kk = fg >> 4;
        const int lbase = ((fg >> 2) & 3) * 16, e0 = (fg & 3) * 2;
        const size_t cb = ((((size_t)n * 4 + jq) * 4 + mfj) * 2 + kk) * 64;
        #pragma unroll
        for (int jj = 0; jj < 4; ++jj) {
            int l16 = (jg * 4 + jj) & 15;
            *(unsigned*)(wf + (cb + lbase + l16) * 8 + e0) = bfpack(acc[jj][0], acc[jj][1]);
        }
        if (fg == 0) {
            #pragma unroll
            for (int jj = 0; jj < 4; ++jj) {
                int j = jq * 64 + jg * 4 + jj;
                ws[OFF_BE2 + n * NH + j] = accb[jj] + b1[j];
            }
        }
        return;
    }
    if (bx < 320) {
        // ---- x -> bf16 B-frag order ----
        int g = (bx - 256) * 512 + t;               // 0..32767
        int b = g >> 3, ko = g & 7;
        float4 v0 = ((const float4*)x)[b * 16 + ko * 2];
        float4 v1 = ((const float4*)x)[b * 16 + ko * 2 + 1];
        union { unsigned u[4]; short8 v; } cv;
        cv.u[0] = bfpack(v0.x, v0.y); cv.u[1] = bfpack(v0.z, v0.w);
        cv.u[2] = bfpack(v1.x, v1.y); cv.u[3] = bfpack(v1.z, v1.w);
        int bt = b >> 6, nf = (b >> 4) & 3, kk = ko >> 2, l = (ko & 3) * 16 + (b & 15);
        ((short8*)(ws + OFF_XBF))[(((size_t)bt * 4 + nf) * 2 + kk) * 64 + l] = cv.v;
        return;
    }
    // ---- Wattn blocks: jt = bx-320 handles j = jt*64..+63 ----
    const int jt = bx - 320;
    float* Ks  = sh;            // [6][128]
    float* WqK = sh + 768;      // [128][8] (pad)
    float* W2t = sh + 1792;     // [64][129]
    for (int q = t; q < NA * NE; q += 512) {
        int a = q >> 7, e2 = q & 127;
        float acc = 0.f;
        for (int e = 0; e < NE; ++e) acc = fmaf(basis[a * NE + e], Wk[e * NE + e2], acc);
        Ks[a * NE + e2] = acc;
    }
    __syncthreads();
    for (int q = t; q < NE * NA; q += 512) {
        int e = q / NA, a = q - e * NA;
        float acc = 0.f;
        for (int e2 = 0; e2 < NE; ++e2) acc = fmaf(Wq[e * NE + e2], Ks[a * NE + e2], acc);
        WqK[e * 8 + a] = acc;
    }
    __syncthreads();
    for (int i = 0; i < 16; ++i) {                  // stage W2 rows jt*64..+63
        int idx = i * 512 + t;
        int jr = idx >> 7, e = idx & 127;
        W2t[jr * 129 + e] = W2[(size_t)(jt * 64 + jr) * NE + e];
    }
    __syncthreads();
    const float scale = 1.f / (sqrtf(128.f) + 1e-8f);
    unsigned short* wf16 = (unsigned short*)(ws + OFF_WATTNF);
    if (t < 256) {
        const int jl = t & 63, ag = t >> 6;
        const int j = jt * 64 + jl;
        const int na = (ag < 2) ? 2 : 1;
        for (int ai = 0; ai < na; ++ai) {
            int a = ag + ai * 4;
            float acc = 0.f;
            for (int e = 0; e < NE; ++e)
                acc = fmaf(W2t[jl * 129 + e], WqK[e * 8 + a], acc);
            wf16[((j >> 3) * 16 + a) * 8 + (j & 7)] = bf16r(acc * scale);
        }
        if (ag == 3) wf16[((j >> 3) * 16 + 6) * 8 + (j & 7)] = bf16r(1.0f);  // ones col
        for (int a7 = 7 + ag; a7 < 16; a7 += 4)
            wf16[((j >> 3) * 16 + a7) * 8 + (j & 7)] = 0;
    }
    if (jt == 0) {
        __syncthreads();
        if (t < NA) {
            float acc = 0.f;
            for (int e = 0; e < NE; ++e) acc = fmaf(b2[e], WqK[e * 8 + t], acc);
            ws[OFF_BATTN + t] = acc * scale;
        }
        if (t < 64) ws[OFF_S + t] = 0.f;
    }
}

// ---------------------------------------------------------------- A:
// block = (g, n): afr/wfr/be2s loaded ONCE, loop over 8 bt tiles with register
// prefetch. GEMM1 (MFMA) -> relu+bias -> shuffle GEMM2 (proven path).
// Epilogue v2: red double-buffered, hi<2 writes only (rows 8..15 were never
// read), ONE barrier per iteration, direct scattered ARAW write (no red2).
// Race audit:
//   red[p] W(iter k, pre-B1) vs red[p] R(iter k, post-B1)      -> B1(k)
//   red[p] R(iter k) vs red[p] W(iter k+2, after B1(k+1))      -> B1(k+1):
//     every wave enters B1(k+1) only after completing its k-reads.
__global__ __launch_bounds__(256) void kA(float* __restrict__ ws) {
    const int g = blockIdx.x, n = blockIdx.y;     // g: 0..7, each covers 8 bt
    const int t = threadIdx.x, w = t >> 6, l = t & 63, lo = l & 15, hi = l >> 4;
    const int j0 = w * 64;
    __shared__ float be2s[256];
    __shared__ float red[2][4][8][64];            // dbuf x wave x a-row x b

    be2s[t] = ws[OFF_BE2 + n * NH + t];

    const short8* Af = (const short8*)(ws + OFF_WE2F);
    const short8* Bf = (const short8*)(ws + OFF_XBF);
    const short8* Wf = (const short8*)(ws + OFF_WATTNF);
    short8 afr[4][2];
    #pragma unroll
    for (int mf = 0; mf < 4; ++mf)
        #pragma unroll
        for (int kk = 0; kk < 2; ++kk)
            afr[mf][kk] = Af[(((size_t)n * 4 + w) * 4 + mf) * 128 + (size_t)kk * 64 + l];
    short8 wfr8[2];
    #pragma unroll
    for (int kk2 = 0; kk2 < 2; ++kk2)
        wfr8[kk2] = Wf[(size_t)(w * 2 + kk2) * 64 + l];

    f32x4 zero = {0.f, 0.f, 0.f, 0.f};
    short8 bcur[4][2], bnxt[4][2];
    #pragma unroll
    for (int nf = 0; nf < 4; ++nf)
        #pragma unroll
        for (int kk = 0; kk < 2; ++kk)
            bcur[nf][kk] = Bf[(((size_t)(g * 8) * 4 + nf) * 2 + kk) * 64 + l];
    float hsacc = 0.f;
    __syncthreads();   // be2s ready

    for (int it = 0; it < 8; ++it) {
        const int bt = g * 8 + it;
        if (it < 7) {   // prefetch next B tile; lands during GEMM1+epilogue
            #pragma unroll
            for (int nf = 0; nf < 4; ++nf)
                #pragma unroll
                for (int kk = 0; kk < 2; ++kk)
                    bnxt[nf][kk] = Bf[(((size_t)(bt + 1) * 4 + nf) * 2 + kk) * 64 + l];
        }

        f32x4 acc[4][4];
        #pragma unroll
        for (int mf = 0; mf < 4; ++mf)
            #pragma unroll
            for (int nf = 0; nf < 4; ++nf) acc[mf][nf] = zero;
        #pragma unroll
        for (int kk = 0; kk < 2; ++kk)
            #pragma unroll
            for (int mf = 0; mf < 4; ++mf)
                #pragma unroll
                for (int nf = 0; nf < 4; ++nf)
                    acc[mf][nf] = __builtin_amdgcn_mfma_f32_16x16x32_bf16(
                        afr[mf][kk], bcur[nf][kk], acc[mf][nf], 0, 0, 0);

        // GEMM2 per kk2: pack only the two mf's it needs (16 P regs live)
        f32x4 acc2[4];
        #pragma unroll
        for (int nf = 0; nf < 4; ++nf) acc2[nf] = zero;
        #pragma unroll
        for (int kk2 = 0; kk2 < 2; ++kk2) {
            unsigned P2[2][4][2];
            #pragma unroll
            for (int dm = 0; dm < 2; ++dm) {
                const int mf = kk2 * 2 + dm;
                const int jb = j0 + mf * 16 + hi * 4;
                #pragma unroll
                for (int nf = 0; nf < 4; ++nf) {
                    float h0 = fmaxf(acc[mf][nf][0] + be2s[jb + 0], 0.f);
                    float h1 = fmaxf(acc[mf][nf][1] + be2s[jb + 1], 0.f);
                    float h2 = fmaxf(acc[mf][nf][2] + be2s[jb + 2], 0.f);
                    float h3 = fmaxf(acc[mf][nf][3] + be2s[jb + 3], 0.f);
                    P2[dm][nf][0] = bfpack(h0, h1);
                    P2[dm][nf][1] = bfpack(h2, h3);
                }
            }
            #pragma unroll
            for (int nf = 0; nf < 4; ++nf) {
                unsigned bq[4];
                #pragma unroll
                for (int q = 0; q < 4; ++q) {
                    int s = ((hi & 1) * 2 + (q >> 1)) * 16 + lo;
                    unsigned vA = (unsigned)__shfl((int)P2[0][nf][q & 1], s, 64);
                    unsigned vB = (unsigned)__shfl((int)P2[1][nf][q & 1], s, 64);
                    bq[q] = (hi >= 2) ? vB : vA;
                }
                union { unsigned u[4]; short8 v; } cv;
                cv.u[0] = bq[0]; cv.u[1] = bq[1]; cv.u[2] = bq[2]; cv.u[3] = bq[3];
                acc2[nf] = __builtin_amdgcn_mfma_f32_16x16x32_bf16(wfr8[kk2], cv.v, acc2[nf], 0, 0, 0);
            }
        }

        // cross-wave partials: only a-rows 0..7 are live
        if (hi < 2) {
            #pragma unroll
            for (int nf = 0; nf < 4; ++nf)
                #pragma unroll
                for (int i = 0; i < 4; ++i)
                    red[it & 1][w][hi * 4 + i][nf * 16 + lo] = acc2[nf][i];
        }
        __syncthreads();                                   // B1 (only barrier)

        const int rb = t & 63, a0 = t >> 6, a1 = a0 + 4;
        const float (*rd)[8][64] = red[it & 1];
        float v0 = rd[0][a0][rb] + rd[1][a0][rb] + rd[2][a0][rb] + rd[3][a0][rb];
        float v1 = rd[0][a1][rb] + rd[1][a1][rb] + rd[2][a1][rb] + rd[3][a1][rb];
        float* ap = ws + OFF_ARAW + ((size_t)(bt * 64 + rb) * 64 + n) * 8;
        ap[a0] = v0;
        ap[a1] = v1;
        if (a1 == 6) {   // wave 2: ones-column = h row-sums
            float hs = v1;
            #pragma unroll
            for (int m = 1; m < 64; m <<= 1) hs += __shfl_xor(hs, m, 64);
            if (l == 0) hsacc += hs;
        }
        if (it < 7) {
            #pragma unroll
            for (int nf = 0; nf < 4; ++nf)
                #pragma unroll
                for (int kk = 0; kk < 2; ++kk)
                    bcur[nf][kk] = bnxt[nf][kk];
        }
    }

    if (w == 2 && l == 0) atomicAdd(ws + OFF_S + n, hsacc);
}

// ---------------------------------------------------------------- C:
// block = one batch row b: thread0 scalar gate chain (c), contiguous 2 KB
// ARAW read via LDS, softmax(6) per token, 32 KB contiguous output write.
__global__ __launch_bounds__(256) void kC(const float* __restrict__ ws,
                                          const float* __restrict__ basis,
                                          const float* __restrict__ mW1, const float* __restrict__ mb1,
                                          const float* __restrict__ mW2, const float* __restrict__ mb2,
                                          const float* __restrict__ gW1, const float* __restrict__ gb1,
                                          const float* __restrict__ gW2, const float* __restrict__ gb2,
                                          float* __restrict__ out) {
    const int b = blockIdx.x;
    const int t = threadIdx.x;
    __shared__ float ars[512];
    __shared__ float sw[64][8];
    __shared__ float bs[6][128];
    __shared__ float csh;
    if (t < 128)
        ((float4*)ars)[t] = ((const float4*)(ws + OFF_ARAW + (size_t)b * 512))[t];
    for (int q = t; q < NA * NE; q += 256) bs[q >> 7][q & 127] = basis[q];
    if (t == 0) {   // scalar gate chain
        float S = 0.f;
        for (int i = 0; i < 64; ++i) S += ws[OFF_S + i];
        float s = S / ((float)NB * NN * NH);
        float accm = mb2[0];
        for (int i = 0; i < 8; ++i) accm += fmaxf(s * mW1[i] + mb1[i], 0.f) * mW2[i];
        float m = 1.f / (1.f + expf(-accm));
        float state = 0.9f * 0.5f + 0.1f * m;
        float c1 = 1.f + 0.1f * (state - 0.5f);
        float sg = c1 * s;
        float accg = gb2[0];
        for (int i = 0; i < 16; ++i) accg += fmaxf(sg * gW1[i] + gb1[i], 0.f) * gW2[i];
        float g = 1.f / (1.f + expf(-accg));
        csh = c1 * g;
    }
    __syncthreads();
    if (t < 64) {
        const float c = csh;
        float at[6], mx = -1e30f;
        #pragma unroll
        for (int a = 0; a < 6; ++a) {
            at[a] = fmaf(c, ars[t * 8 + a], ws[OFF_BATTN + a]);
            mx = fmaxf(mx, at[a]);
        }
        float ex[6], ssum = 0.f;
        #pragma unroll
        for (int a = 0; a < 6; ++a) { ex[a] = expf(at[a] - mx); ssum += ex[a]; }
        float inv = 1.f / ssum;
        #pragma unroll
        for (int a = 0; a < 6; ++a) sw[t][a] = ex[a] * inv;
    }
    __syncthreads();
    float* op = out + (size_t)b * (NN * NE);
    #pragma unroll
    for (int i = 0; i < 8; ++i) {
        int idx = i * 1024 + t * 4;          // 0..8191
        int n = idx >> 7, e = idx & 127;
        float wv[6];
        #pragma unroll
        for (int a = 0; a < 6; ++a) wv[a] = sw[n][a];
        float4 r;
        #pragma unroll
        for (int cc = 0; cc < 4; ++cc) {
            float o = 0.f;
            #pragma unroll
            for (int a = 0; a < 6; ++a) o = fmaf(wv[a], bs[a][e + cc], o);
            ((float*)&r)[cc] = fminf(fmaxf(o, -3.f), 3.f);
        }
        *(float4*)(op + idx) = r;
    }
}

extern "C" void kernel_launch(void* const* d_in, const int* in_sizes, int n_in,
                              void* d_out, int out_size, void* d_ws, size_t ws_size,
                              hipStream_t stream) {
    const float* x     = (const float*)d_in[0];
    const float* Wemb  = (const float*)d_in[1];
    const float* bemb  = (const float*)d_in[2];
    const float* adjw  = (const float*)d_in[3];
    const float* W1    = (const float*)d_in[4];
    const float* b1    = (const float*)d_in[5];
    const float* W2    = (const float*)d_in[6];
    const float* b2    = (const float*)d_in[7];
    const float* basis = (const float*)d_in[8];
    const float* Wq    = (const float*)d_in[9];
    const float* Wk    = (const float*)d_in[10];
    const float* mW1   = (const float*)d_in[11];
    const float* mb1   = (const float*)d_in[12];
    const float* mW2   = (const float*)d_in[13];
    const float* mb2   = (const float*)d_in[14];
    const float* gW1   = (const float*)d_in[15];
    const float* gb1   = (const float*)d_in[16];
    const float* gW2   = (const float*)d_in[17];
    const float* gb2   = (const float*)d_in[18];
    float* ws  = (float*)d_ws;
    float* out = (float*)d_out;

    kP<<<324, 512, 0, stream>>>(x, Wemb, bemb, adjw, W1, b1, basis, Wq, Wk, W2, b2, ws);
    kA<<<dim3(8, 64), 256, 0, stream>>>(ws);
    kC<<<NB, 256, 0, stream>>>(ws, basis, mW1, mb1, mW2, mb2, gW1, gb1, gW2, gb2, out);
}